// Round 1
// baseline (12720.943 us; speedup 1.0000x reference)
//
#include <hip/hip_runtime.h>
#include <hip/hip_bf16.h>
#include <math.h>

#define NN 16384
#define EE 262144
#define DIN 144
#define F1d 128
#define F2d 64
#define F3d 32

// ---------- float <-> ordered-uint encoding for atomic min/max ----------
__device__ __forceinline__ unsigned enc_f(float f){
  unsigned u = __float_as_uint(f);
  return (u & 0x80000000u) ? ~u : (u | 0x80000000u);
}
__device__ __forceinline__ float dec_f(unsigned u){
  return __uint_as_float((u & 0x80000000u) ? (u ^ 0x80000000u) : ~u);
}

// ---------- init: zero deg arrays, small accumulators, hist; set min/max ----------
__global__ void init_kernel(int* __restrict__ deg, float* __restrict__ smallf,
                            unsigned* __restrict__ mm_hist){
  int t = blockIdx.x * 256 + threadIdx.x;
  if (t < 2 * NN) deg[t] = 0;
  if (t < 1024) smallf[t] = 0.f;
  if (t == 0){ mm_hist[0] = 0xFFFFFFFFu; mm_hist[1] = 0u; }
  if (t >= 2 && t < 18) mm_hist[t] = 0u;
}

// ---------- degree count over edge rows ----------
__global__ void deg_count(const int* __restrict__ row, int* __restrict__ deg){
  int e = blockIdx.x * 256 + threadIdx.x;
  if (e < EE) atomicAdd(&deg[row[e]], 1);
}

// ---------- exclusive scan of deg[NN] -> rp[0..NN]  (single block, 1024 thr) ----------
__global__ void scan_kernel(const int* __restrict__ deg, int* __restrict__ rp){
  __shared__ int part[1024];
  int t = threadIdx.x;
  int base = t * 16;
  int v[16]; int s = 0;
#pragma unroll
  for (int i = 0; i < 16; i++){ v[i] = deg[base + i]; s += v[i]; }
  part[t] = s;
  __syncthreads();
  for (int off = 1; off < 1024; off <<= 1){
    int x = (t >= off) ? part[t - off] : 0;
    __syncthreads();
    part[t] += x;
    __syncthreads();
  }
  int excl = part[t] - s;
#pragma unroll
  for (int i = 0; i < 16; i++){ rp[base + i] = excl; excl += v[i]; }
  if (t == 1023) rp[NN] = part[1023];
}

// ---------- dinv = 1/sqrt(deg+1); cursor init ----------
__global__ void dinv_cur(const int* __restrict__ deg, const int* __restrict__ rp,
                         float* __restrict__ dinv, int* __restrict__ cur){
  int i = blockIdx.x * 256 + threadIdx.x;
  if (i < NN){
    dinv[i] = 1.0f / sqrtf((float)(deg[i] + 1));
    cur[i] = rp[i];
  }
}

// ---------- CSR fill ----------
__global__ void fill_kernel(const int* __restrict__ ei, int* __restrict__ cur,
                            int* __restrict__ col){
  int e = blockIdx.x * 256 + threadIdx.x;
  if (e < EE){
    int r = ei[e];
    int pos = atomicAdd(&cur[r], 1);
    col[pos] = ei[EE + e];
  }
}

// ---------- hs = dinv[i] * (x @ W) ----------
template<int KD, int FD>
__global__ __launch_bounds__(256) void gemm_hs(const float* __restrict__ X,
                                               const float* __restrict__ W,
                                               const float* __restrict__ dinv,
                                               float* __restrict__ HS){
  constexpr int KC = 16;
  constexpr int ROWS = 16;
  constexpr int G = 256 / FD;    // row slots per block
  constexpr int R = ROWS / G;    // rows per thread
  __shared__ float xs[ROWS][KC];
  __shared__ float ws[KC][FD];
  int t = threadIdx.x;
  int f = t % FD;
  int rs = t / FD;
  int row0 = blockIdx.x * ROWS;
  float acc[R];
#pragma unroll
  for (int r = 0; r < R; r++) acc[r] = 0.f;
  for (int k0 = 0; k0 < KD; k0 += KC){
    __syncthreads();
    for (int idx = t; idx < KC * FD; idx += 256){
      int kk = idx / FD, ff = idx % FD;
      ws[kk][ff] = W[(k0 + kk) * FD + ff];
    }
    {
      int rr = t / KC, kk = t % KC;
      xs[rr][kk] = X[(row0 + rr) * KD + k0 + kk];
    }
    __syncthreads();
#pragma unroll
    for (int kk = 0; kk < KC; kk++){
      float wv = ws[kk][f];
#pragma unroll
      for (int r = 0; r < R; r++)
        acc[r] += xs[rs * R + r][kk] * wv;
    }
  }
#pragma unroll
  for (int r = 0; r < R; r++){
    int row = row0 + rs * R + r;
    HS[row * FD + f] = dinv[row] * acc[r];
  }
}

// ---------- out[i] = dinv[i]*(hs[i] + sum_nbr hs[j]) + b  (+relu) ----------
template<int FD, bool RELU>
__global__ __launch_bounds__(256) void agg_kernel(const float* __restrict__ HS,
                                                  const int* __restrict__ rp,
                                                  const int* __restrict__ col,
                                                  const float* __restrict__ dinv,
                                                  const float* __restrict__ b,
                                                  float* __restrict__ OUT){
  constexpr int NPB = 256 / FD;
  int t = threadIdx.x;
  int f = t % FD;
  int i = blockIdx.x * NPB + t / FD;
  float acc = HS[i * FD + f];
  int p0 = rp[i], p1 = rp[i + 1];
  for (int p = p0; p < p1; p++){
    int j = col[p];
    acc += HS[j * FD + f];
  }
  float o = dinv[i] * acc + b[f];
  if (RELU) o = fmaxf(o, 0.f);
  OUT[i * FD + f] = o;
}

// ---------- column sums of af (N x 32) ----------
__global__ void colsum_kernel(const float* __restrict__ AF, float* __restrict__ out){
  __shared__ float s[32];
  int t = threadIdx.x;
  if (t < 32) s[t] = 0.f;
  __syncthreads();
  int f = t % 32;
  int slot = t / 32;
  float a = 0.f;
  for (int i = blockIdx.x * 8 + slot; i < NN; i += gridDim.x * 8)
    a += AF[i * 32 + f];
  atomicAdd(&s[f], a);
  __syncthreads();
  if (t < 32) atomicAdd(&out[t], s[t]);
}

// ---------- tg = tanh( (colsum/N) @ att_W ) ----------
__global__ void tg_kernel(const float* __restrict__ colsum, const float* __restrict__ attW,
                          float* __restrict__ tg){
  int f = threadIdx.x;
  float s = 0.f;
  for (int g = 0; g < 32; g++)
    s += (colsum[g] * (1.f / (float)NN)) * attW[g * 32 + f];
  tg[f] = tanhf(s);
}

// ---------- pooled = af^T @ sigmoid(af @ tg) ----------
__global__ void pool_kernel(const float* __restrict__ AF, const float* __restrict__ tg,
                            float* __restrict__ pooled){
  int t = threadIdx.x;
  int f = t % 32;
  int slot = t / 32;
  float tgv = tg[f];
  float acc = 0.f;
  for (int i = blockIdx.x * 8 + slot; i < NN; i += gridDim.x * 8){
    float v = AF[i * 32 + f];
    float d = v * tgv;
#pragma unroll
    for (int o = 16; o >= 1; o >>= 1) d += __shfl_xor(d, o, 32);
    float gate = 1.f / (1.f + expf(-d));
    acc += v * gate;
  }
  __shared__ float s[32];
  if (t < 32) s[t] = 0.f;
  __syncthreads();
  atomicAdd(&s[f], acc);
  __syncthreads();
  if (t < 32) atomicAdd(&pooled[t], s[t]);
}

// ---------- sim = af1 @ af2^T tiles; PASS 1: min/max, PASS 2: histogram ----------
template<int PASS>
__global__ __launch_bounds__(256) void sim_kernel(const float* __restrict__ A,
                                                  const float* __restrict__ B,
                                                  const float* __restrict__ edges,
                                                  unsigned* __restrict__ mm,
                                                  unsigned* __restrict__ hist){
  __shared__ float As[32][129];
  __shared__ float Bs[32][129];
  int t = threadIdx.x;
  int i0 = blockIdx.x * 128, j0 = blockIdx.y * 128;
  for (int idx = t; idx < 4096; idx += 256){
    int r = idx >> 5;       // 0..127
    int k = idx & 31;       // 0..31
    As[k][r] = A[(i0 + r) * 32 + k];
    Bs[k][r] = B[(j0 + r) * 32 + k];
  }
  __syncthreads();
  int tx = t % 16, ty = t / 16;
  float acc[8][8] = {};
#pragma unroll
  for (int k = 0; k < 32; k++){
    float a[8], b[8];
#pragma unroll
    for (int u = 0; u < 8; u++) a[u] = As[k][ty * 8 + u];
#pragma unroll
    for (int u = 0; u < 8; u++) b[u] = Bs[k][tx * 8 + u];
#pragma unroll
    for (int u = 0; u < 8; u++)
#pragma unroll
      for (int v = 0; v < 8; v++)
        acc[u][v] += a[u] * b[v];
  }

  if (PASS == 1){
    float mn = acc[0][0], mx = acc[0][0];
#pragma unroll
    for (int u = 0; u < 8; u++)
#pragma unroll
      for (int v = 0; v < 8; v++){
        mn = fminf(mn, acc[u][v]);
        mx = fmaxf(mx, acc[u][v]);
      }
#pragma unroll
    for (int o = 32; o >= 1; o >>= 1){
      mn = fminf(mn, __shfl_xor(mn, o));
      mx = fmaxf(mx, __shfl_xor(mx, o));
    }
    if ((t & 63) == 0){
      atomicMin(&mm[0], enc_f(mn));
      atomicMax(&mm[1], enc_f(mx));
    }
  } else {
    float lo = edges[0], sc = edges[1];
    unsigned long long p0 = 0ull, p1 = 0ull;
#pragma unroll
    for (int u = 0; u < 8; u++)
#pragma unroll
      for (int v = 0; v < 8; v++){
        float x = acc[u][v];
        int idx = (int)((x - lo) * sc);
        idx = idx < 0 ? 0 : (idx > 15 ? 15 : idx);
        unsigned long long inc = 1ull << ((idx & 7) << 3);
        if (idx < 8) p0 += inc; else p1 += inc;
      }
    const unsigned long long M = 0x00ff00ff00ff00ffull;
    unsigned long long e0 = p0 & M;           // bins 0,2,4,6
    unsigned long long e1 = (p0 >> 8) & M;    // bins 1,3,5,7
    unsigned long long e2 = p1 & M;           // bins 8,10,12,14
    unsigned long long e3 = (p1 >> 8) & M;    // bins 9,11,13,15
#pragma unroll
    for (int o = 32; o >= 1; o >>= 1){
      e0 += __shfl_xor(e0, o);
      e1 += __shfl_xor(e1, o);
      e2 += __shfl_xor(e2, o);
      e3 += __shfl_xor(e3, o);
    }
    if ((t & 63) == 0){
#pragma unroll
      for (int q = 0; q < 4; q++){
        atomicAdd(&hist[0 + 2 * q], (unsigned)((e0 >> (16 * q)) & 0xFFFFull));
        atomicAdd(&hist[1 + 2 * q], (unsigned)((e1 >> (16 * q)) & 0xFFFFull));
        atomicAdd(&hist[8 + 2 * q], (unsigned)((e2 >> (16 * q)) & 0xFFFFull));
        atomicAdd(&hist[9 + 2 * q], (unsigned)((e3 >> (16 * q)) & 0xFFFFull));
      }
    }
  }
}

// ---------- compute bin edges from min/max ----------
__global__ void edges_kernel(const unsigned* __restrict__ mm, float* __restrict__ edges){
  float lo = dec_f(mm[0]);
  float hi = dec_f(mm[1]);
  edges[0] = lo;
  edges[1] = (hi > lo) ? (16.f / (hi - lo)) : 0.f;
}

// ---------- tensor network + hist concat + fc + sigmoid ----------
__global__ void final_kernel(const float* __restrict__ pooled1, const float* __restrict__ pooled2,
                             const float* __restrict__ tW, const float* __restrict__ tWb,
                             const float* __restrict__ tb, const unsigned* __restrict__ hist,
                             const float* __restrict__ fcW, const float* __restrict__ fcb,
                             const float* __restrict__ scW, const float* __restrict__ scb,
                             float* __restrict__ out){
  __shared__ float e1[32], e2[32], v[32], u[16];
  int t = threadIdx.x;
  if (t < 32){ e1[t] = pooled1[t]; e2[t] = pooled2[t]; }
  __syncthreads();
  if (t < 16){
    float s = 0.f;
    for (int a = 0; a < 32; a++){
      float ea = e1[a];
      for (int b = 0; b < 32; b++)
        s += ea * tW[(a * 32 + b) * 16 + t] * e2[b];
    }
    float blk = 0.f;
    for (int a = 0; a < 32; a++) blk += tWb[t * 64 + a] * e1[a];
    for (int b = 0; b < 32; b++) blk += tWb[t * 64 + 32 + b] * e2[b];
    float r = s + blk + tb[t];
    v[t] = r > 0.f ? r : 0.f;
  }
  __syncthreads();
  if (t == 0){
    float tot = 0.f;
    for (int i = 0; i < 16; i++) tot += (float)hist[i];
    float inv = 1.f / tot;
    for (int i = 0; i < 16; i++) v[16 + i] = (float)hist[i] * inv;
  }
  __syncthreads();
  if (t < 16){
    float s = fcb[t];
    for (int i = 0; i < 32; i++) s += fcW[t * 32 + i] * v[i];
    u[t] = s > 0.f ? s : 0.f;
  }
  __syncthreads();
  if (t == 0){
    float s = scb[0];
    for (int i = 0; i < 16; i++) s += scW[i] * u[i];
    out[0] = 1.f / (1.f + expf(-s));
  }
}

extern "C" void kernel_launch(void* const* d_in, const int* in_sizes, int n_in,
                              void* d_out, int out_size, void* d_ws, size_t ws_size,
                              hipStream_t stream){
  const float* feat[2] = {(const float*)d_in[0], (const float*)d_in[1]};
  const int*   ei[2]   = {(const int*)d_in[2], (const int*)d_in[3]};
  const float* W1  = (const float*)d_in[4];
  const float* b1  = (const float*)d_in[5];
  const float* W2  = (const float*)d_in[6];
  const float* b2  = (const float*)d_in[7];
  const float* W3  = (const float*)d_in[8];
  const float* b3  = (const float*)d_in[9];
  const float* attW = (const float*)d_in[10];
  const float* tW  = (const float*)d_in[11];
  const float* tWb = (const float*)d_in[12];
  const float* tb  = (const float*)d_in[13];
  const float* fcW = (const float*)d_in[14];
  const float* fcb = (const float*)d_in[15];
  const float* scW = (const float*)d_in[16];
  const float* scb = (const float*)d_in[17];

  char* w = (char*)d_ws;
  size_t o = 0;
  auto alloc = [&](size_t bytes)->char*{
    char* p = w + o; o += (bytes + 255) & ~(size_t)255; return p;
  };
  int* deg = (int*)alloc((size_t)2 * NN * 4);
  float* dinv[2]; int* rp[2]; int* cur[2]; int* col[2];
  for (int g = 0; g < 2; g++){
    dinv[g] = (float*)alloc((size_t)NN * 4);
    rp[g]   = (int*)alloc((size_t)(NN + 1) * 4);
    cur[g]  = (int*)alloc((size_t)NN * 4);
    col[g]  = (int*)alloc((size_t)EE * 4);
  }
  float* hbuf = (float*)alloc((size_t)NN * F1d * 4);
  float* abuf = (float*)alloc((size_t)NN * F1d * 4);
  float* af[2] = {(float*)alloc((size_t)NN * F3d * 4), (float*)alloc((size_t)NN * F3d * 4)};
  float* smallf = (float*)alloc(1024 * 4);
  unsigned* mm_hist = (unsigned*)alloc(32 * 4);

  float* colsum[2] = {smallf + 0,  smallf + 96};
  float* tg[2]     = {smallf + 32, smallf + 128};
  float* pooled[2] = {smallf + 64, smallf + 160};
  float* edg = smallf + 192;

  init_kernel<<<128, 256, 0, stream>>>(deg, smallf, mm_hist);

  for (int g = 0; g < 2; g++){
    int* degg = deg + g * NN;
    deg_count<<<EE / 256, 256, 0, stream>>>(ei[g], degg);
    scan_kernel<<<1, 1024, 0, stream>>>(degg, rp[g]);
    dinv_cur<<<NN / 256, 256, 0, stream>>>(degg, rp[g], dinv[g], cur[g]);
    fill_kernel<<<EE / 256, 256, 0, stream>>>(ei[g], cur[g], col[g]);

    gemm_hs<DIN, F1d><<<NN / 16, 256, 0, stream>>>(feat[g], W1, dinv[g], hbuf);
    agg_kernel<F1d, true><<<NN / 2, 256, 0, stream>>>(hbuf, rp[g], col[g], dinv[g], b1, abuf);
    gemm_hs<F1d, F2d><<<NN / 16, 256, 0, stream>>>(abuf, W2, dinv[g], hbuf);
    agg_kernel<F2d, true><<<NN / 4, 256, 0, stream>>>(hbuf, rp[g], col[g], dinv[g], b2, abuf);
    gemm_hs<F2d, F3d><<<NN / 16, 256, 0, stream>>>(abuf, W3, dinv[g], hbuf);
    agg_kernel<F3d, false><<<NN / 8, 256, 0, stream>>>(hbuf, rp[g], col[g], dinv[g], b3, af[g]);

    colsum_kernel<<<128, 256, 0, stream>>>(af[g], colsum[g]);
    tg_kernel<<<1, 32, 0, stream>>>(colsum[g], attW, tg[g]);
    pool_kernel<<<128, 256, 0, stream>>>(af[g], tg[g], pooled[g]);
  }

  dim3 simgrid(128, 128);
  sim_kernel<1><<<simgrid, 256, 0, stream>>>(af[0], af[1], edg, mm_hist, mm_hist + 2);
  edges_kernel<<<1, 1, 0, stream>>>(mm_hist, edg);
  sim_kernel<2><<<simgrid, 256, 0, stream>>>(af[0], af[1], edg, mm_hist, mm_hist + 2);

  final_kernel<<<1, 64, 0, stream>>>(pooled[0], pooled[1], tW, tWb, tb, mm_hist + 2,
                                     fcW, fcb, scW, scb, (float*)d_out);
}

// Round 2
// 12589.368 us; speedup vs baseline: 1.0105x; 1.0105x over previous
//
#include <hip/hip_runtime.h>
#include <hip/hip_bf16.h>
#include <math.h>

#define NN 16384
#define EE 262144
#define DIN 144
#define F1d 128
#define F2d 64
#define F3d 32

typedef __attribute__((ext_vector_type(8))) short bf16x8;
typedef __attribute__((ext_vector_type(4))) float f32x4;

// ---------- float <-> ordered-uint encoding for atomic min/max ----------
__device__ __forceinline__ unsigned enc_f(float f){
  unsigned u = __float_as_uint(f);
  return (u & 0x80000000u) ? ~u : (u | 0x80000000u);
}
__device__ __forceinline__ float dec_f(unsigned u){
  return __uint_as_float((u & 0x80000000u) ? (u ^ 0x80000000u) : ~u);
}
__device__ __forceinline__ unsigned short f2bf(float f){
  unsigned u = __float_as_uint(f);
  unsigned r = (u + 0x7fffu + ((u >> 16) & 1u)) >> 16;   // RNE
  return (unsigned short)r;
}

// ---------- init: zero deg arrays, small accumulators, hist; set min/max ----------
__global__ void init_kernel(int* __restrict__ deg, float* __restrict__ smallf,
                            unsigned* __restrict__ mm_hist){
  int t = blockIdx.x * 256 + threadIdx.x;
  if (t < 2 * NN) deg[t] = 0;
  if (t < 1024) smallf[t] = 0.f;
  if (t == 0){ mm_hist[0] = 0xFFFFFFFFu; mm_hist[1] = 0u; }
  if (t >= 2 && t < 18) mm_hist[t] = 0u;
}

// ---------- degree count over edge rows ----------
__global__ void deg_count(const int* __restrict__ row, int* __restrict__ deg){
  int e = blockIdx.x * 256 + threadIdx.x;
  if (e < EE) atomicAdd(&deg[row[e]], 1);
}

// ---------- exclusive scan of deg[NN] -> rp[0..NN]  (single block, 1024 thr) ----------
__global__ void scan_kernel(const int* __restrict__ deg, int* __restrict__ rp){
  __shared__ int part[1024];
  int t = threadIdx.x;
  int base = t * 16;
  int v[16]; int s = 0;
#pragma unroll
  for (int i = 0; i < 16; i++){ v[i] = deg[base + i]; s += v[i]; }
  part[t] = s;
  __syncthreads();
  for (int off = 1; off < 1024; off <<= 1){
    int x = (t >= off) ? part[t - off] : 0;
    __syncthreads();
    part[t] += x;
    __syncthreads();
  }
  int excl = part[t] - s;
#pragma unroll
  for (int i = 0; i < 16; i++){ rp[base + i] = excl; excl += v[i]; }
  if (t == 1023) rp[NN] = part[1023];
}

// ---------- dinv = 1/sqrt(deg+1); cursor init ----------
__global__ void dinv_cur(const int* __restrict__ deg, const int* __restrict__ rp,
                         float* __restrict__ dinv, int* __restrict__ cur){
  int i = blockIdx.x * 256 + threadIdx.x;
  if (i < NN){
    dinv[i] = 1.0f / sqrtf((float)(deg[i] + 1));
    cur[i] = rp[i];
  }
}

// ---------- CSR fill ----------
__global__ void fill_kernel(const int* __restrict__ ei, int* __restrict__ cur,
                            int* __restrict__ col){
  int e = blockIdx.x * 256 + threadIdx.x;
  if (e < EE){
    int r = ei[e];
    int pos = atomicAdd(&cur[r], 1);
    col[pos] = ei[EE + e];
  }
}

// ---------- hs = dinv[i] * (x @ W) ----------
template<int KD, int FD>
__global__ __launch_bounds__(256) void gemm_hs(const float* __restrict__ X,
                                               const float* __restrict__ W,
                                               const float* __restrict__ dinv,
                                               float* __restrict__ HS){
  constexpr int KC = 16;
  constexpr int ROWS = 16;
  constexpr int G = 256 / FD;    // row slots per block
  constexpr int R = ROWS / G;    // rows per thread
  __shared__ float xs[ROWS][KC];
  __shared__ float ws[KC][FD];
  int t = threadIdx.x;
  int f = t % FD;
  int rs = t / FD;
  int row0 = blockIdx.x * ROWS;
  float acc[R];
#pragma unroll
  for (int r = 0; r < R; r++) acc[r] = 0.f;
  for (int k0 = 0; k0 < KD; k0 += KC){
    __syncthreads();
    for (int idx = t; idx < KC * FD; idx += 256){
      int kk = idx / FD, ff = idx % FD;
      ws[kk][ff] = W[(k0 + kk) * FD + ff];
    }
    {
      int rr = t / KC, kk = t % KC;
      xs[rr][kk] = X[(row0 + rr) * KD + k0 + kk];
    }
    __syncthreads();
#pragma unroll
    for (int kk = 0; kk < KC; kk++){
      float wv = ws[kk][f];
#pragma unroll
      for (int r = 0; r < R; r++)
        acc[r] += xs[rs * R + r][kk] * wv;
    }
  }
#pragma unroll
  for (int r = 0; r < R; r++){
    int row = row0 + rs * R + r;
    HS[row * FD + f] = dinv[row] * acc[r];
  }
}

// ---------- out[i] = dinv[i]*(hs[i] + sum_nbr hs[j]) + b  (+relu) ----------
template<int FD, bool RELU>
__global__ __launch_bounds__(256) void agg_kernel(const float* __restrict__ HS,
                                                  const int* __restrict__ rp,
                                                  const int* __restrict__ col,
                                                  const float* __restrict__ dinv,
                                                  const float* __restrict__ b,
                                                  float* __restrict__ OUT){
  constexpr int NPB = 256 / FD;
  int t = threadIdx.x;
  int f = t % FD;
  int i = blockIdx.x * NPB + t / FD;
  float acc = HS[i * FD + f];
  int p0 = rp[i], p1 = rp[i + 1];
  for (int p = p0; p < p1; p++){
    int j = col[p];
    acc += HS[j * FD + f];
  }
  float o = dinv[i] * acc + b[f];
  if (RELU) o = fmaxf(o, 0.f);
  OUT[i * FD + f] = o;
}

// ---------- cast af fp32 -> bf16 (RNE) ----------
__global__ void cast_bf16(const float* __restrict__ in, unsigned short* __restrict__ out,
                          int n){
  int i = (blockIdx.x * 256 + threadIdx.x) * 4;
  if (i < n){
    float4 v = *(const float4*)(in + i);
    ushort4 o;
    o.x = f2bf(v.x); o.y = f2bf(v.y); o.z = f2bf(v.z); o.w = f2bf(v.w);
    *(ushort4*)(out + i) = o;
  }
}

// ---------- column sums of af (N x 32) ----------
__global__ void colsum_kernel(const float* __restrict__ AF, float* __restrict__ out){
  __shared__ float s[32];
  int t = threadIdx.x;
  if (t < 32) s[t] = 0.f;
  __syncthreads();
  int f = t % 32;
  int slot = t / 32;
  float a = 0.f;
  for (int i = blockIdx.x * 8 + slot; i < NN; i += gridDim.x * 8)
    a += AF[i * 32 + f];
  atomicAdd(&s[f], a);
  __syncthreads();
  if (t < 32) atomicAdd(&out[t], s[t]);
}

// ---------- tg = tanh( (colsum/N) @ att_W ) ----------
__global__ void tg_kernel(const float* __restrict__ colsum, const float* __restrict__ attW,
                          float* __restrict__ tg){
  int f = threadIdx.x;
  float s = 0.f;
  for (int g = 0; g < 32; g++)
    s += (colsum[g] * (1.f / (float)NN)) * attW[g * 32 + f];
  tg[f] = tanhf(s);
}

// ---------- pooled = af^T @ sigmoid(af @ tg) ----------
__global__ void pool_kernel(const float* __restrict__ AF, const float* __restrict__ tg,
                            float* __restrict__ pooled){
  int t = threadIdx.x;
  int f = t % 32;
  int slot = t / 32;
  float tgv = tg[f];
  float acc = 0.f;
  for (int i = blockIdx.x * 8 + slot; i < NN; i += gridDim.x * 8){
    float v = AF[i * 32 + f];
    float d = v * tgv;
#pragma unroll
    for (int o = 16; o >= 1; o >>= 1) d += __shfl_xor(d, o, 32);
    float gate = 1.f / (1.f + expf(-d));
    acc += v * gate;
  }
  __shared__ float s[32];
  if (t < 32) s[t] = 0.f;
  __syncthreads();
  atomicAdd(&s[f], acc);
  __syncthreads();
  if (t < 32) atomicAdd(&pooled[t], s[t]);
}

// ---------- sim = af1 @ af2^T via bf16 MFMA; PASS 1: min/max, PASS 2: histogram ----
// Block = 256 thr = 4 waves arranged 2x2; block tile 128x128; wave tile 64x64
// (4x4 of 16x16 MFMA tiles). K=32 == one mfma_f32_16x16x32_bf16 per tile pair.
// A-frag: lane l holds A[m=l&15][k=(l>>4)*8 + 0..7] -> 16B contiguous global load.
// B-frag (B = af2^T): lane l holds af2[n=l&15][k=(l>>4)*8 + 0..7] -> same pattern.
// C/D layout irrelevant: we only bin/minmax the 64 values per lane.
template<int PASS>
__global__ __launch_bounds__(256) void sim_mfma(const unsigned short* __restrict__ A,
                                                const unsigned short* __restrict__ B,
                                                const float* __restrict__ edges,
                                                unsigned* __restrict__ mm,
                                                unsigned* __restrict__ hist){
  int t = threadIdx.x;
  int l = t & 63, w = t >> 6;
  int wr = w >> 1, wc = w & 1;
  int i0 = blockIdx.x * 128 + wr * 64;
  int j0 = blockIdx.y * 128 + wc * 64;
  int m  = l & 15;
  int k0 = (l >> 4) * 8;

  bf16x8 a[4], b[4];
#pragma unroll
  for (int u = 0; u < 4; u++){
    a[u] = *(const bf16x8*)(A + (size_t)(i0 + u * 16 + m) * 32 + k0);
    b[u] = *(const bf16x8*)(B + (size_t)(j0 + u * 16 + m) * 32 + k0);
  }

  f32x4 acc[4][4];
#pragma unroll
  for (int u = 0; u < 4; u++)
#pragma unroll
    for (int v = 0; v < 4; v++){
      f32x4 z = {0.f, 0.f, 0.f, 0.f};
      acc[u][v] = __builtin_amdgcn_mfma_f32_16x16x32_bf16(a[u], b[v], z, 0, 0, 0);
    }

  if (PASS == 1){
    float mn = acc[0][0][0], mx = acc[0][0][0];
#pragma unroll
    for (int u = 0; u < 4; u++)
#pragma unroll
      for (int v = 0; v < 4; v++)
#pragma unroll
        for (int r = 0; r < 4; r++){
          float x = acc[u][v][r];
          mn = fminf(mn, x);
          mx = fmaxf(mx, x);
        }
#pragma unroll
    for (int o = 32; o >= 1; o >>= 1){
      mn = fminf(mn, __shfl_xor(mn, o));
      mx = fmaxf(mx, __shfl_xor(mx, o));
    }
    if (l == 0){
      atomicMin(&mm[0], enc_f(mn));
      atomicMax(&mm[1], enc_f(mx));
    }
  } else {
    float lo = edges[0], sc = edges[1];
    unsigned long long p0 = 0ull, p1 = 0ull;
#pragma unroll
    for (int u = 0; u < 4; u++)
#pragma unroll
      for (int v = 0; v < 4; v++)
#pragma unroll
        for (int r = 0; r < 4; r++){
          float x = acc[u][v][r];
          int idx = (int)((x - lo) * sc);
          idx = idx < 0 ? 0 : (idx > 15 ? 15 : idx);
          unsigned long long inc = 1ull << ((idx & 7) << 3);
          if (idx < 8) p0 += inc; else p1 += inc;
        }
    const unsigned long long M = 0x00ff00ff00ff00ffull;
    unsigned long long e0 = p0 & M;           // bins 0,2,4,6
    unsigned long long e1 = (p0 >> 8) & M;    // bins 1,3,5,7
    unsigned long long e2 = p1 & M;           // bins 8,10,12,14
    unsigned long long e3 = (p1 >> 8) & M;    // bins 9,11,13,15
#pragma unroll
    for (int o = 32; o >= 1; o >>= 1){
      e0 += __shfl_xor(e0, o);
      e1 += __shfl_xor(e1, o);
      e2 += __shfl_xor(e2, o);
      e3 += __shfl_xor(e3, o);
    }
    if (l == 0){
#pragma unroll
      for (int q = 0; q < 4; q++){
        atomicAdd(&hist[0 + 2 * q], (unsigned)((e0 >> (16 * q)) & 0xFFFFull));
        atomicAdd(&hist[1 + 2 * q], (unsigned)((e1 >> (16 * q)) & 0xFFFFull));
        atomicAdd(&hist[8 + 2 * q], (unsigned)((e2 >> (16 * q)) & 0xFFFFull));
        atomicAdd(&hist[9 + 2 * q], (unsigned)((e3 >> (16 * q)) & 0xFFFFull));
      }
    }
  }
}

// ---------- compute bin edges from min/max ----------
__global__ void edges_kernel(const unsigned* __restrict__ mm, float* __restrict__ edges){
  float lo = dec_f(mm[0]);
  float hi = dec_f(mm[1]);
  edges[0] = lo;
  edges[1] = (hi > lo) ? (16.f / (hi - lo)) : 0.f;
}

// ---------- tensor network + hist concat + fc + sigmoid ----------
__global__ void final_kernel(const float* __restrict__ pooled1, const float* __restrict__ pooled2,
                             const float* __restrict__ tW, const float* __restrict__ tWb,
                             const float* __restrict__ tb, const unsigned* __restrict__ hist,
                             const float* __restrict__ fcW, const float* __restrict__ fcb,
                             const float* __restrict__ scW, const float* __restrict__ scb,
                             float* __restrict__ out){
  __shared__ float e1[32], e2[32], v[32], u[16];
  int t = threadIdx.x;
  if (t < 32){ e1[t] = pooled1[t]; e2[t] = pooled2[t]; }
  __syncthreads();
  if (t < 16){
    float s = 0.f;
    for (int a = 0; a < 32; a++){
      float ea = e1[a];
      for (int b = 0; b < 32; b++)
        s += ea * tW[(a * 32 + b) * 16 + t] * e2[b];
    }
    float blk = 0.f;
    for (int a = 0; a < 32; a++) blk += tWb[t * 64 + a] * e1[a];
    for (int b = 0; b < 32; b++) blk += tWb[t * 64 + 32 + b] * e2[b];
    float r = s + blk + tb[t];
    v[t] = r > 0.f ? r : 0.f;
  }
  __syncthreads();
  if (t == 0){
    float tot = 0.f;
    for (int i = 0; i < 16; i++) tot += (float)hist[i];
    float inv = 1.f / tot;
    for (int i = 0; i < 16; i++) v[16 + i] = (float)hist[i] * inv;
  }
  __syncthreads();
  if (t < 16){
    float s = fcb[t];
    for (int i = 0; i < 32; i++) s += fcW[t * 32 + i] * v[i];
    u[t] = s > 0.f ? s : 0.f;
  }
  __syncthreads();
  if (t == 0){
    float s = scb[0];
    for (int i = 0; i < 16; i++) s += scW[i] * u[i];
    out[0] = 1.f / (1.f + expf(-s));
  }
}

extern "C" void kernel_launch(void* const* d_in, const int* in_sizes, int n_in,
                              void* d_out, int out_size, void* d_ws, size_t ws_size,
                              hipStream_t stream){
  const float* feat[2] = {(const float*)d_in[0], (const float*)d_in[1]};
  const int*   ei[2]   = {(const int*)d_in[2], (const int*)d_in[3]};
  const float* W1  = (const float*)d_in[4];
  const float* b1  = (const float*)d_in[5];
  const float* W2  = (const float*)d_in[6];
  const float* b2  = (const float*)d_in[7];
  const float* W3  = (const float*)d_in[8];
  const float* b3  = (const float*)d_in[9];
  const float* attW = (const float*)d_in[10];
  const float* tW  = (const float*)d_in[11];
  const float* tWb = (const float*)d_in[12];
  const float* tb  = (const float*)d_in[13];
  const float* fcW = (const float*)d_in[14];
  const float* fcb = (const float*)d_in[15];
  const float* scW = (const float*)d_in[16];
  const float* scb = (const float*)d_in[17];

  char* w = (char*)d_ws;
  size_t o = 0;
  auto alloc = [&](size_t bytes)->char*{
    char* p = w + o; o += (bytes + 255) & ~(size_t)255; return p;
  };
  int* deg = (int*)alloc((size_t)2 * NN * 4);
  float* dinv[2]; int* rp[2]; int* cur[2]; int* col[2];
  for (int g = 0; g < 2; g++){
    dinv[g] = (float*)alloc((size_t)NN * 4);
    rp[g]   = (int*)alloc((size_t)(NN + 1) * 4);
    cur[g]  = (int*)alloc((size_t)NN * 4);
    col[g]  = (int*)alloc((size_t)EE * 4);
  }
  float* hbuf = (float*)alloc((size_t)NN * F1d * 4);
  float* abuf = (float*)alloc((size_t)NN * F1d * 4);
  float* af[2] = {(float*)alloc((size_t)NN * F3d * 4), (float*)alloc((size_t)NN * F3d * 4)};
  unsigned short* afb[2] = {(unsigned short*)alloc((size_t)NN * F3d * 2),
                            (unsigned short*)alloc((size_t)NN * F3d * 2)};
  float* smallf = (float*)alloc(1024 * 4);
  unsigned* mm_hist = (unsigned*)alloc(32 * 4);

  float* colsum[2] = {smallf + 0,  smallf + 96};
  float* tg[2]     = {smallf + 32, smallf + 128};
  float* pooled[2] = {smallf + 64, smallf + 160};
  float* edg = smallf + 192;

  init_kernel<<<128, 256, 0, stream>>>(deg, smallf, mm_hist);

  for (int g = 0; g < 2; g++){
    int* degg = deg + g * NN;
    deg_count<<<EE / 256, 256, 0, stream>>>(ei[g], degg);
    scan_kernel<<<1, 1024, 0, stream>>>(degg, rp[g]);
    dinv_cur<<<NN / 256, 256, 0, stream>>>(degg, rp[g], dinv[g], cur[g]);
    fill_kernel<<<EE / 256, 256, 0, stream>>>(ei[g], cur[g], col[g]);

    gemm_hs<DIN, F1d><<<NN / 16, 256, 0, stream>>>(feat[g], W1, dinv[g], hbuf);
    agg_kernel<F1d, true><<<NN / 2, 256, 0, stream>>>(hbuf, rp[g], col[g], dinv[g], b1, abuf);
    gemm_hs<F1d, F2d><<<NN / 16, 256, 0, stream>>>(abuf, W2, dinv[g], hbuf);
    agg_kernel<F2d, true><<<NN / 4, 256, 0, stream>>>(hbuf, rp[g], col[g], dinv[g], b2, abuf);
    gemm_hs<F2d, F3d><<<NN / 16, 256, 0, stream>>>(abuf, W3, dinv[g], hbuf);
    agg_kernel<F3d, false><<<NN / 8, 256, 0, stream>>>(hbuf, rp[g], col[g], dinv[g], b3, af[g]);

    cast_bf16<<<NN * F3d / 1024, 256, 0, stream>>>(af[g], afb[g], NN * F3d);
    colsum_kernel<<<128, 256, 0, stream>>>(af[g], colsum[g]);
    tg_kernel<<<1, 32, 0, stream>>>(colsum[g], attW, tg[g]);
    pool_kernel<<<128, 256, 0, stream>>>(af[g], tg[g], pooled[g]);
  }

  dim3 simgrid(128, 128);
  sim_mfma<1><<<simgrid, 256, 0, stream>>>(afb[0], afb[1], edg, mm_hist, mm_hist + 2);
  edges_kernel<<<1, 1, 0, stream>>>(mm_hist, edg);
  sim_mfma<2><<<simgrid, 256, 0, stream>>>(afb[0], afb[1], edg, mm_hist, mm_hist + 2);

  final_kernel<<<1, 64, 0, stream>>>(pooled[0], pooled[1], tW, tWb, tb, mm_hist + 2,
                                     fcW, fcb, scW, scb, (float*)d_out);
}

// Round 3
// 748.403 us; speedup vs baseline: 16.9975x; 16.8217x over previous
//
#include <hip/hip_runtime.h>
#include <hip/hip_bf16.h>
#include <math.h>

#define NN 16384
#define EE 262144
#define DIN 144
#define F1d 128
#define F2d 64
#define F3d 32

#define SIM_BLOCKS 1024   // persistent sim grid; 4096 waves; each wave: 1 i-strip x 16 j-tiles

typedef __attribute__((ext_vector_type(8))) short bf16x8;
typedef __attribute__((ext_vector_type(4))) float f32x4;

__device__ __forceinline__ unsigned short f2bf(float f){
  unsigned u = __float_as_uint(f);
  unsigned r = (u + 0x7fffu + ((u >> 16) & 1u)) >> 16;   // RNE
  return (unsigned short)r;
}

// ---------- init: zero deg arrays + small accumulators ----------
__global__ void init_kernel(int* __restrict__ deg, float* __restrict__ smallf){
  int t = blockIdx.x * 256 + threadIdx.x;
  if (t < 2 * NN) deg[t] = 0;
  if (t < 1024) smallf[t] = 0.f;
}

// ---------- degree count over edge rows ----------
__global__ void deg_count(const int* __restrict__ row, int* __restrict__ deg){
  int e = blockIdx.x * 256 + threadIdx.x;
  if (e < EE) atomicAdd(&deg[row[e]], 1);
}

// ---------- exclusive scan of deg[NN] -> rp[0..NN]  (single block, 1024 thr) ----------
__global__ void scan_kernel(const int* __restrict__ deg, int* __restrict__ rp){
  __shared__ int part[1024];
  int t = threadIdx.x;
  int base = t * 16;
  int v[16]; int s = 0;
#pragma unroll
  for (int i = 0; i < 16; i++){ v[i] = deg[base + i]; s += v[i]; }
  part[t] = s;
  __syncthreads();
  for (int off = 1; off < 1024; off <<= 1){
    int x = (t >= off) ? part[t - off] : 0;
    __syncthreads();
    part[t] += x;
    __syncthreads();
  }
  int excl = part[t] - s;
#pragma unroll
  for (int i = 0; i < 16; i++){ rp[base + i] = excl; excl += v[i]; }
  if (t == 1023) rp[NN] = part[1023];
}

// ---------- dinv = 1/sqrt(deg+1); cursor init ----------
__global__ void dinv_cur(const int* __restrict__ deg, const int* __restrict__ rp,
                         float* __restrict__ dinv, int* __restrict__ cur){
  int i = blockIdx.x * 256 + threadIdx.x;
  if (i < NN){
    dinv[i] = 1.0f / sqrtf((float)(deg[i] + 1));
    cur[i] = rp[i];
  }
}

// ---------- CSR fill ----------
__global__ void fill_kernel(const int* __restrict__ ei, int* __restrict__ cur,
                            int* __restrict__ col){
  int e = blockIdx.x * 256 + threadIdx.x;
  if (e < EE){
    int r = ei[e];
    int pos = atomicAdd(&cur[r], 1);
    col[pos] = ei[EE + e];
  }
}

// ---------- hs = dinv[i] * (x @ W) ----------
template<int KD, int FD>
__global__ __launch_bounds__(256) void gemm_hs(const float* __restrict__ X,
                                               const float* __restrict__ W,
                                               const float* __restrict__ dinv,
                                               float* __restrict__ HS){
  constexpr int KC = 16;
  constexpr int ROWS = 16;
  constexpr int G = 256 / FD;    // row slots per block
  constexpr int R = ROWS / G;    // rows per thread
  __shared__ float xs[ROWS][KC];
  __shared__ float ws[KC][FD];
  int t = threadIdx.x;
  int f = t % FD;
  int rs = t / FD;
  int row0 = blockIdx.x * ROWS;
  float acc[R];
#pragma unroll
  for (int r = 0; r < R; r++) acc[r] = 0.f;
  for (int k0 = 0; k0 < KD; k0 += KC){
    __syncthreads();
    for (int idx = t; idx < KC * FD; idx += 256){
      int kk = idx / FD, ff = idx % FD;
      ws[kk][ff] = W[(k0 + kk) * FD + ff];
    }
    {
      int rr = t / KC, kk = t % KC;
      xs[rr][kk] = X[(row0 + rr) * KD + k0 + kk];
    }
    __syncthreads();
#pragma unroll
    for (int kk = 0; kk < KC; kk++){
      float wv = ws[kk][f];
#pragma unroll
      for (int r = 0; r < R; r++)
        acc[r] += xs[rs * R + r][kk] * wv;
    }
  }
#pragma unroll
  for (int r = 0; r < R; r++){
    int row = row0 + rs * R + r;
    HS[row * FD + f] = dinv[row] * acc[r];
  }
}

// ---------- out[i] = dinv[i]*(hs[i] + sum_nbr hs[j]) + b  (+relu) ----------
template<int FD, bool RELU>
__global__ __launch_bounds__(256) void agg_kernel(const float* __restrict__ HS,
                                                  const int* __restrict__ rp,
                                                  const int* __restrict__ col,
                                                  const float* __restrict__ dinv,
                                                  const float* __restrict__ b,
                                                  float* __restrict__ OUT){
  constexpr int NPB = 256 / FD;
  int t = threadIdx.x;
  int f = t % FD;
  int i = blockIdx.x * NPB + t / FD;
  float acc = HS[i * FD + f];
  int p0 = rp[i], p1 = rp[i + 1];
  for (int p = p0; p < p1; p++){
    int j = col[p];
    acc += HS[j * FD + f];
  }
  float o = dinv[i] * acc + b[f];
  if (RELU) o = fmaxf(o, 0.f);
  OUT[i * FD + f] = o;
}

// ---------- cast af fp32 -> bf16 (RNE) ----------
__global__ void cast_bf16(const float* __restrict__ in, unsigned short* __restrict__ out,
                          int n){
  int i = (blockIdx.x * 256 + threadIdx.x) * 4;
  if (i < n){
    float4 v = *(const float4*)(in + i);
    ushort4 o;
    o.x = f2bf(v.x); o.y = f2bf(v.y); o.z = f2bf(v.z); o.w = f2bf(v.w);
    *(ushort4*)(out + i) = o;
  }
}

// ---------- column sums of af (N x 32) ----------
__global__ void colsum_kernel(const float* __restrict__ AF, float* __restrict__ out){
  __shared__ float s[32];
  int t = threadIdx.x;
  if (t < 32) s[t] = 0.f;
  __syncthreads();
  int f = t % 32;
  int slot = t / 32;
  float a = 0.f;
  for (int i = blockIdx.x * 8 + slot; i < NN; i += gridDim.x * 8)
    a += AF[i * 32 + f];
  atomicAdd(&s[f], a);
  __syncthreads();
  if (t < 32) atomicAdd(&out[t], s[t]);
}

// ---------- tg = tanh( (colsum/N) @ att_W ) ----------
__global__ void tg_kernel(const float* __restrict__ colsum, const float* __restrict__ attW,
                          float* __restrict__ tg){
  int f = threadIdx.x;
  float s = 0.f;
  for (int g = 0; g < 32; g++)
    s += (colsum[g] * (1.f / (float)NN)) * attW[g * 32 + f];
  tg[f] = tanhf(s);
}

// ---------- pooled = af^T @ sigmoid(af @ tg) ----------
__global__ void pool_kernel(const float* __restrict__ AF, const float* __restrict__ tg,
                            float* __restrict__ pooled){
  int t = threadIdx.x;
  int f = t % 32;
  int slot = t / 32;
  float tgv = tg[f];
  float acc = 0.f;
  for (int i = blockIdx.x * 8 + slot; i < NN; i += gridDim.x * 8){
    float v = AF[i * 32 + f];
    float d = v * tgv;
#pragma unroll
    for (int o = 16; o >= 1; o >>= 1) d += __shfl_xor(d, o, 32);
    float gate = 1.f / (1.f + expf(-d));
    acc += v * gate;
  }
  __shared__ float s[32];
  if (t < 32) s[t] = 0.f;
  __syncthreads();
  atomicAdd(&s[f], acc);
  __syncthreads();
  if (t < 32) atomicAdd(&pooled[t], s[t]);
}

// ================= sim = af1 @ af2^T, persistent, ATOMIC-FREE =================
// Grid: SIM_BLOCKS x 256 thr (4 waves). wave_id in [0,4096): i-strip = wave_id>>4
// (64 rows, A-frags loaded once), j-group = wave_id&15 -> 16 j-tiles of 64 cols.
// Per j-tile: 16x mfma_f32_16x16x32_bf16 (K=32 in one shot, frags straight from
// global, 16B/lane). Values are binned per-lane; block partials written to
// DISTINCT global slots (no atomics anywhere; round-2 lesson: 1M same-line
// atomics serialized = 10.6 ms).
template<int PASS>
__global__ __launch_bounds__(256) void sim_mfma(const unsigned short* __restrict__ A,
                                                const unsigned short* __restrict__ B,
                                                const float* __restrict__ edges,
                                                float* __restrict__ pmm,      // [SIM_BLOCKS*2]
                                                unsigned* __restrict__ phist){ // [SIM_BLOCKS*16]
  int t = threadIdx.x;
  int l = t & 63, w = t >> 6;
  int wave_id = blockIdx.x * 4 + w;
  int istrip = wave_id >> 4;
  int jgrp = wave_id & 15;
  int i0 = istrip * 64;
  int m  = l & 15;
  int k0 = (l >> 4) * 8;

  bf16x8 a[4];
#pragma unroll
  for (int u = 0; u < 4; u++)
    a[u] = *(const bf16x8*)(A + (size_t)(i0 + u * 16 + m) * 32 + k0);

  float mn = 3.402823466e38f, mx = -3.402823466e38f;
  unsigned cnt[16];
#pragma unroll
  for (int q = 0; q < 16; q++) cnt[q] = 0u;
  float lo = 0.f, sc = 0.f;
  if (PASS == 2){ lo = edges[0]; sc = edges[1]; }

  for (int jj = 0; jj < 16; jj++){
    int j0 = (jgrp * 16 + jj) * 64;
    bf16x8 b[4];
#pragma unroll
    for (int v = 0; v < 4; v++)
      b[v] = *(const bf16x8*)(B + (size_t)(j0 + v * 16 + m) * 32 + k0);

    if (PASS == 1){
#pragma unroll
      for (int u = 0; u < 4; u++)
#pragma unroll
        for (int v = 0; v < 4; v++){
          f32x4 z = {0.f, 0.f, 0.f, 0.f};
          f32x4 acc = __builtin_amdgcn_mfma_f32_16x16x32_bf16(a[u], b[v], z, 0, 0, 0);
#pragma unroll
          for (int r = 0; r < 4; r++){
            mn = fminf(mn, acc[r]);
            mx = fmaxf(mx, acc[r]);
          }
        }
    } else {
      unsigned long long p0 = 0ull, p1 = 0ull;
#pragma unroll
      for (int u = 0; u < 4; u++)
#pragma unroll
        for (int v = 0; v < 4; v++){
          f32x4 z = {0.f, 0.f, 0.f, 0.f};
          f32x4 acc = __builtin_amdgcn_mfma_f32_16x16x32_bf16(a[u], b[v], z, 0, 0, 0);
#pragma unroll
          for (int r = 0; r < 4; r++){
            int idx = (int)((acc[r] - lo) * sc);
            idx = idx < 0 ? 0 : (idx > 15 ? 15 : idx);
            unsigned long long inc = 1ull << ((idx & 7) << 3);
            if (idx < 8) p0 += inc; else p1 += inc;
          }
        }
      // expand packed 8-bit fields (max 64 per field this tile) into u32 counters
#pragma unroll
      for (int q = 0; q < 8; q++){
        cnt[q]     += (unsigned)((p0 >> (8 * q)) & 0xffull);
        cnt[8 + q] += (unsigned)((p1 >> (8 * q)) & 0xffull);
      }
    }
  }

  if (PASS == 1){
#pragma unroll
    for (int o = 32; o >= 1; o >>= 1){
      mn = fminf(mn, __shfl_xor(mn, o));
      mx = fmaxf(mx, __shfl_xor(mx, o));
    }
    __shared__ float wmn[4], wmx[4];
    if (l == 0){ wmn[w] = mn; wmx[w] = mx; }
    __syncthreads();
    if (t == 0){
      float bmn = fminf(fminf(wmn[0], wmn[1]), fminf(wmn[2], wmn[3]));
      float bmx = fmaxf(fmaxf(wmx[0], wmx[1]), fmaxf(wmx[2], wmx[3]));
      pmm[blockIdx.x * 2]     = bmn;
      pmm[blockIdx.x * 2 + 1] = bmx;
    }
  } else {
    // reduce 16 counters across the 64 lanes
#pragma unroll
    for (int q = 0; q < 16; q++){
#pragma unroll
      for (int o = 32; o >= 1; o >>= 1)
        cnt[q] += (unsigned)__shfl_xor((int)cnt[q], o);
    }
    __shared__ unsigned wcnt[4][16];
    if (l == 0){
#pragma unroll
      for (int q = 0; q < 16; q++) wcnt[w][q] = cnt[q];
    }
    __syncthreads();
    if (t < 16)
      phist[blockIdx.x * 16 + t] = wcnt[0][t] + wcnt[1][t] + wcnt[2][t] + wcnt[3][t];
  }
}

// ---------- reduce per-block min/max partials -> bin edges ----------
__global__ void edges_kernel(const float* __restrict__ pmm, float* __restrict__ edges){
  int t = threadIdx.x;
  float mn = 3.402823466e38f, mx = -3.402823466e38f;
  for (int b = t; b < SIM_BLOCKS; b += 256){
    mn = fminf(mn, pmm[b * 2]);
    mx = fmaxf(mx, pmm[b * 2 + 1]);
  }
#pragma unroll
  for (int o = 32; o >= 1; o >>= 1){
    mn = fminf(mn, __shfl_xor(mn, o));
    mx = fmaxf(mx, __shfl_xor(mx, o));
  }
  __shared__ float wmn[4], wmx[4];
  if ((t & 63) == 0){ wmn[t >> 6] = mn; wmx[t >> 6] = mx; }
  __syncthreads();
  if (t == 0){
    float lo = fminf(fminf(wmn[0], wmn[1]), fminf(wmn[2], wmn[3]));
    float hi = fmaxf(fmaxf(wmx[0], wmx[1]), fmaxf(wmx[2], wmx[3]));
    edges[0] = lo;
    edges[1] = (hi > lo) ? (16.f / (hi - lo)) : 0.f;
  }
}

// ---------- reduce per-block hist partials -> hist[16] ----------
__global__ void hist_reduce(const unsigned* __restrict__ phist, unsigned* __restrict__ hist){
  int t = threadIdx.x;          // 256 threads
  int bin = t & 15, part = t >> 4;
  unsigned s = 0;
  for (int b = part; b < SIM_BLOCKS; b += 16)
    s += phist[b * 16 + bin];
  __shared__ unsigned tmp[256];
  tmp[t] = s;
  __syncthreads();
  if (t < 16){
    unsigned tot = 0;
#pragma unroll
    for (int p = 0; p < 16; p++) tot += tmp[p * 16 + t];
    hist[t] = tot;
  }
}

// ---------- tensor network + hist concat + fc + sigmoid ----------
__global__ void final_kernel(const float* __restrict__ pooled1, const float* __restrict__ pooled2,
                             const float* __restrict__ tW, const float* __restrict__ tWb,
                             const float* __restrict__ tb, const unsigned* __restrict__ hist,
                             const float* __restrict__ fcW, const float* __restrict__ fcb,
                             const float* __restrict__ scW, const float* __restrict__ scb,
                             float* __restrict__ out){
  __shared__ float e1[32], e2[32], v[32], u[16];
  int t = threadIdx.x;
  if (t < 32){ e1[t] = pooled1[t]; e2[t] = pooled2[t]; }
  __syncthreads();
  if (t < 16){
    float s = 0.f;
    for (int a = 0; a < 32; a++){
      float ea = e1[a];
      for (int b = 0; b < 32; b++)
        s += ea * tW[(a * 32 + b) * 16 + t] * e2[b];
    }
    float blk = 0.f;
    for (int a = 0; a < 32; a++) blk += tWb[t * 64 + a] * e1[a];
    for (int b = 0; b < 32; b++) blk += tWb[t * 64 + 32 + b] * e2[b];
    float r = s + blk + tb[t];
    v[t] = r > 0.f ? r : 0.f;
  }
  __syncthreads();
  if (t == 0){
    float tot = 0.f;
    for (int i = 0; i < 16; i++) tot += (float)hist[i];
    float inv = 1.f / tot;
    for (int i = 0; i < 16; i++) v[16 + i] = (float)hist[i] * inv;
  }
  __syncthreads();
  if (t < 16){
    float s = fcb[t];
    for (int i = 0; i < 32; i++) s += fcW[t * 32 + i] * v[i];
    u[t] = s > 0.f ? s : 0.f;
  }
  __syncthreads();
  if (t == 0){
    float s = scb[0];
    for (int i = 0; i < 16; i++) s += scW[i] * u[i];
    out[0] = 1.f / (1.f + expf(-s));
  }
}

extern "C" void kernel_launch(void* const* d_in, const int* in_sizes, int n_in,
                              void* d_out, int out_size, void* d_ws, size_t ws_size,
                              hipStream_t stream){
  const float* feat[2] = {(const float*)d_in[0], (const float*)d_in[1]};
  const int*   ei[2]   = {(const int*)d_in[2], (const int*)d_in[3]};
  const float* W1  = (const float*)d_in[4];
  const float* b1  = (const float*)d_in[5];
  const float* W2  = (const float*)d_in[6];
  const float* b2  = (const float*)d_in[7];
  const float* W3  = (const float*)d_in[8];
  const float* b3  = (const float*)d_in[9];
  const float* attW = (const float*)d_in[10];
  const float* tW  = (const float*)d_in[11];
  const float* tWb = (const float*)d_in[12];
  const float* tb  = (const float*)d_in[13];
  const float* fcW = (const float*)d_in[14];
  const float* fcb = (const float*)d_in[15];
  const float* scW = (const float*)d_in[16];
  const float* scb = (const float*)d_in[17];

  char* w = (char*)d_ws;
  size_t o = 0;
  auto alloc = [&](size_t bytes)->char*{
    char* p = w + o; o += (bytes + 255) & ~(size_t)255; return p;
  };
  int* deg = (int*)alloc((size_t)2 * NN * 4);
  float* dinv[2]; int* rp[2]; int* cur[2]; int* col[2];
  for (int g = 0; g < 2; g++){
    dinv[g] = (float*)alloc((size_t)NN * 4);
    rp[g]   = (int*)alloc((size_t)(NN + 1) * 4);
    cur[g]  = (int*)alloc((size_t)NN * 4);
    col[g]  = (int*)alloc((size_t)EE * 4);
  }
  float* hbuf = (float*)alloc((size_t)NN * F1d * 4);
  float* abuf = (float*)alloc((size_t)NN * F1d * 4);
  float* af[2] = {(float*)alloc((size_t)NN * F3d * 4), (float*)alloc((size_t)NN * F3d * 4)};
  unsigned short* afb[2] = {(unsigned short*)alloc((size_t)NN * F3d * 2),
                            (unsigned short*)alloc((size_t)NN * F3d * 2)};
  float* pmm = (float*)alloc((size_t)SIM_BLOCKS * 2 * 4);
  unsigned* phist = (unsigned*)alloc((size_t)SIM_BLOCKS * 16 * 4);
  unsigned* hist = (unsigned*)alloc(16 * 4);
  float* smallf = (float*)alloc(1024 * 4);

  float* colsum[2] = {smallf + 0,  smallf + 96};
  float* tg[2]     = {smallf + 32, smallf + 128};
  float* pooled[2] = {smallf + 64, smallf + 160};
  float* edg = smallf + 192;

  init_kernel<<<128, 256, 0, stream>>>(deg, smallf);

  for (int g = 0; g < 2; g++){
    int* degg = deg + g * NN;
    deg_count<<<EE / 256, 256, 0, stream>>>(ei[g], degg);
    scan_kernel<<<1, 1024, 0, stream>>>(degg, rp[g]);
    dinv_cur<<<NN / 256, 256, 0, stream>>>(degg, rp[g], dinv[g], cur[g]);
    fill_kernel<<<EE / 256, 256, 0, stream>>>(ei[g], cur[g], col[g]);

    gemm_hs<DIN, F1d><<<NN / 16, 256, 0, stream>>>(feat[g], W1, dinv[g], hbuf);
    agg_kernel<F1d, true><<<NN / 2, 256, 0, stream>>>(hbuf, rp[g], col[g], dinv[g], b1, abuf);
    gemm_hs<F1d, F2d><<<NN / 16, 256, 0, stream>>>(abuf, W2, dinv[g], hbuf);
    agg_kernel<F2d, true><<<NN / 4, 256, 0, stream>>>(hbuf, rp[g], col[g], dinv[g], b2, abuf);
    gemm_hs<F2d, F3d><<<NN / 16, 256, 0, stream>>>(abuf, W3, dinv[g], hbuf);
    agg_kernel<F3d, false><<<NN / 8, 256, 0, stream>>>(hbuf, rp[g], col[g], dinv[g], b3, af[g]);

    cast_bf16<<<NN * F3d / 1024, 256, 0, stream>>>(af[g], afb[g], NN * F3d);
    colsum_kernel<<<128, 256, 0, stream>>>(af[g], colsum[g]);
    tg_kernel<<<1, 32, 0, stream>>>(colsum[g], attW, tg[g]);
    pool_kernel<<<128, 256, 0, stream>>>(af[g], tg[g], pooled[g]);
  }

  sim_mfma<1><<<SIM_BLOCKS, 256, 0, stream>>>(afb[0], afb[1], edg, pmm, phist);
  edges_kernel<<<1, 256, 0, stream>>>(pmm, edg);
  sim_mfma<2><<<SIM_BLOCKS, 256, 0, stream>>>(afb[0], afb[1], edg, pmm, phist);
  hist_reduce<<<1, 256, 0, stream>>>(phist, hist);

  final_kernel<<<1, 64, 0, stream>>>(pooled[0], pooled[1], tW, tWb, tb, hist,
                                     fcW, fcb, scW, scb, (float*)d_out);
}

// Round 4
// 558.030 us; speedup vs baseline: 22.7962x; 1.3412x over previous
//
#include <hip/hip_runtime.h>
#include <hip/hip_bf16.h>
#include <math.h>

#define NN 16384
#define EE 262144
#define DIN 144
#define F1d 128
#define F2d 64
#define F3d 32

#define SIM_BLOCKS 1024   // persistent sim grid; 4096 waves; each wave: 1 i-strip x 16 j-tiles

typedef __attribute__((ext_vector_type(8))) short bf16x8;
typedef __attribute__((ext_vector_type(4))) float f32x4;

__device__ __forceinline__ unsigned short f2bf(float f){
  unsigned u = __float_as_uint(f);
  unsigned r = (u + 0x7fffu + ((u >> 16) & 1u)) >> 16;   // RNE
  return (unsigned short)r;
}

// ---------- init: zero deg arrays + small accumulators ----------
__global__ void init_kernel(int* __restrict__ deg, float* __restrict__ smallf){
  int t = blockIdx.x * 256 + threadIdx.x;
  if (t < 2 * NN) deg[t] = 0;
  if (t < 1024) smallf[t] = 0.f;
}

// ---------- degree count over edge rows ----------
__global__ void deg_count(const int* __restrict__ row, int* __restrict__ deg){
  int e = blockIdx.x * 256 + threadIdx.x;
  if (e < EE) atomicAdd(&deg[row[e]], 1);
}

// ---------- exclusive scan of deg[NN] -> rp[0..NN]  (single block, 1024 thr) ----------
__global__ void scan_kernel(const int* __restrict__ deg, int* __restrict__ rp){
  __shared__ int part[1024];
  int t = threadIdx.x;
  int base = t * 16;
  int v[16]; int s = 0;
#pragma unroll
  for (int i = 0; i < 16; i++){ v[i] = deg[base + i]; s += v[i]; }
  part[t] = s;
  __syncthreads();
  for (int off = 1; off < 1024; off <<= 1){
    int x = (t >= off) ? part[t - off] : 0;
    __syncthreads();
    part[t] += x;
    __syncthreads();
  }
  int excl = part[t] - s;
#pragma unroll
  for (int i = 0; i < 16; i++){ rp[base + i] = excl; excl += v[i]; }
  if (t == 1023) rp[NN] = part[1023];
}

// ---------- dinv = 1/sqrt(deg+1); cursor init ----------
__global__ void dinv_cur(const int* __restrict__ deg, const int* __restrict__ rp,
                         float* __restrict__ dinv, int* __restrict__ cur){
  int i = blockIdx.x * 256 + threadIdx.x;
  if (i < NN){
    dinv[i] = 1.0f / sqrtf((float)(deg[i] + 1));
    cur[i] = rp[i];
  }
}

// ---------- CSR fill ----------
__global__ void fill_kernel(const int* __restrict__ ei, int* __restrict__ cur,
                            int* __restrict__ col){
  int e = blockIdx.x * 256 + threadIdx.x;
  if (e < EE){
    int r = ei[e];
    int pos = atomicAdd(&cur[r], 1);
    col[pos] = ei[EE + e];
  }
}

// ---------- hs = dinv[i] * (x @ W) ----------
template<int KD, int FD>
__global__ __launch_bounds__(256) void gemm_hs(const float* __restrict__ X,
                                               const float* __restrict__ W,
                                               const float* __restrict__ dinv,
                                               float* __restrict__ HS){
  constexpr int KC = 16;
  constexpr int ROWS = 16;
  constexpr int G = 256 / FD;    // row slots per block
  constexpr int R = ROWS / G;    // rows per thread
  __shared__ float xs[ROWS][KC];
  __shared__ float ws[KC][FD];
  int t = threadIdx.x;
  int f = t % FD;
  int rs = t / FD;
  int row0 = blockIdx.x * ROWS;
  float acc[R];
#pragma unroll
  for (int r = 0; r < R; r++) acc[r] = 0.f;
  for (int k0 = 0; k0 < KD; k0 += KC){
    __syncthreads();
    for (int idx = t; idx < KC * FD; idx += 256){
      int kk = idx / FD, ff = idx % FD;
      ws[kk][ff] = W[(k0 + kk) * FD + ff];
    }
    {
      int rr = t / KC, kk = t % KC;
      xs[rr][kk] = X[(row0 + rr) * KD + k0 + kk];
    }
    __syncthreads();
#pragma unroll
    for (int kk = 0; kk < KC; kk++){
      float wv = ws[kk][f];
#pragma unroll
      for (int r = 0; r < R; r++)
        acc[r] += xs[rs * R + r][kk] * wv;
    }
  }
#pragma unroll
  for (int r = 0; r < R; r++){
    int row = row0 + rs * R + r;
    HS[row * FD + f] = dinv[row] * acc[r];
  }
}

// ---------- out[i] = dinv[i]*(hs[i] + sum_nbr hs[j]) + b  (+relu), float4 ----------
template<int FD, bool RELU>
__global__ __launch_bounds__(256) void agg_kernel(const float* __restrict__ HS,
                                                  const int* __restrict__ rp,
                                                  const int* __restrict__ col,
                                                  const float* __restrict__ dinv,
                                                  const float* __restrict__ b,
                                                  float* __restrict__ OUT){
  constexpr int TPN = FD / 4;          // threads per node
  constexpr int NPB = 256 / TPN;       // nodes per block
  int t = threadIdx.x;
  int f4 = t % TPN;
  int i = blockIdx.x * NPB + t / TPN;
  const float4* HS4 = (const float4*)HS;
  float4 acc = HS4[(size_t)i * TPN + f4];
  int p0 = rp[i], p1 = rp[i + 1];
  for (int p = p0; p < p1; p++){
    int j = col[p];
    float4 h = HS4[(size_t)j * TPN + f4];
    acc.x += h.x; acc.y += h.y; acc.z += h.z; acc.w += h.w;
  }
  float di = dinv[i];
  float4 bb = ((const float4*)b)[f4];
  float4 o;
  o.x = di * acc.x + bb.x;
  o.y = di * acc.y + bb.y;
  o.z = di * acc.z + bb.z;
  o.w = di * acc.w + bb.w;
  if (RELU){
    o.x = fmaxf(o.x, 0.f); o.y = fmaxf(o.y, 0.f);
    o.z = fmaxf(o.z, 0.f); o.w = fmaxf(o.w, 0.f);
  }
  ((float4*)OUT)[(size_t)i * TPN + f4] = o;
}

// ---------- cast af fp32 -> bf16 (RNE) ----------
__global__ void cast_bf16(const float* __restrict__ in, unsigned short* __restrict__ out,
                          int n){
  int i = (blockIdx.x * 256 + threadIdx.x) * 4;
  if (i < n){
    float4 v = *(const float4*)(in + i);
    ushort4 o;
    o.x = f2bf(v.x); o.y = f2bf(v.y); o.z = f2bf(v.z); o.w = f2bf(v.w);
    *(ushort4*)(out + i) = o;
  }
}

// ---------- column sums of af (N x 32) ----------
__global__ void colsum_kernel(const float* __restrict__ AF, float* __restrict__ out){
  __shared__ float s[32];
  int t = threadIdx.x;
  if (t < 32) s[t] = 0.f;
  __syncthreads();
  int f = t % 32;
  int slot = t / 32;
  float a = 0.f;
  for (int i = blockIdx.x * 8 + slot; i < NN; i += gridDim.x * 8)
    a += AF[i * 32 + f];
  atomicAdd(&s[f], a);
  __syncthreads();
  if (t < 32) atomicAdd(&out[t], s[t]);
}

// ---------- tg = tanh( (colsum/N) @ att_W ) ----------
__global__ void tg_kernel(const float* __restrict__ colsum, const float* __restrict__ attW,
                          float* __restrict__ tg){
  int f = threadIdx.x;
  float s = 0.f;
  for (int g = 0; g < 32; g++)
    s += (colsum[g] * (1.f / (float)NN)) * attW[g * 32 + f];
  tg[f] = tanhf(s);
}

// ---------- pooled = af^T @ sigmoid(af @ tg) ----------
__global__ void pool_kernel(const float* __restrict__ AF, const float* __restrict__ tg,
                            float* __restrict__ pooled){
  int t = threadIdx.x;
  int f = t % 32;
  int slot = t / 32;
  float tgv = tg[f];
  float acc = 0.f;
  for (int i = blockIdx.x * 8 + slot; i < NN; i += gridDim.x * 8){
    float v = AF[i * 32 + f];
    float d = v * tgv;
#pragma unroll
    for (int o = 16; o >= 1; o >>= 1) d += __shfl_xor(d, o, 32);
    float gate = 1.f / (1.f + expf(-d));
    acc += v * gate;
  }
  __shared__ float s[32];
  if (t < 32) s[t] = 0.f;
  __syncthreads();
  atomicAdd(&s[f], acc);
  __syncthreads();
  if (t < 32) atomicAdd(&pooled[t], s[t]);
}

// ================= sim = af1 @ af2^T, persistent, ATOMIC-FREE =================
template<int PASS>
__global__ __launch_bounds__(256) void sim_mfma(const unsigned short* __restrict__ A,
                                                const unsigned short* __restrict__ B,
                                                const float* __restrict__ edges,
                                                float* __restrict__ pmm,      // [SIM_BLOCKS*2]
                                                unsigned* __restrict__ phist){ // [SIM_BLOCKS*16]
  int t = threadIdx.x;
  int l = t & 63, w = t >> 6;
  int wave_id = blockIdx.x * 4 + w;
  int istrip = wave_id >> 4;
  int jgrp = wave_id & 15;
  int i0 = istrip * 64;
  int m  = l & 15;
  int k0 = (l >> 4) * 8;

  bf16x8 a[4];
#pragma unroll
  for (int u = 0; u < 4; u++)
    a[u] = *(const bf16x8*)(A + (size_t)(i0 + u * 16 + m) * 32 + k0);

  float mn = 3.402823466e38f, mx = -3.402823466e38f;
  unsigned cnt[16];
#pragma unroll
  for (int q = 0; q < 16; q++) cnt[q] = 0u;
  float lo = 0.f, sc = 0.f;
  if (PASS == 2){ lo = edges[0]; sc = edges[1]; }

  for (int jj = 0; jj < 16; jj++){
    int j0 = (jgrp * 16 + jj) * 64;
    bf16x8 b[4];
#pragma unroll
    for (int v = 0; v < 4; v++)
      b[v] = *(const bf16x8*)(B + (size_t)(j0 + v * 16 + m) * 32 + k0);

    if (PASS == 1){
#pragma unroll
      for (int u = 0; u < 4; u++)
#pragma unroll
        for (int v = 0; v < 4; v++){
          f32x4 z = {0.f, 0.f, 0.f, 0.f};
          f32x4 acc = __builtin_amdgcn_mfma_f32_16x16x32_bf16(a[u], b[v], z, 0, 0, 0);
#pragma unroll
          for (int r = 0; r < 4; r++){
            mn = fminf(mn, acc[r]);
            mx = fmaxf(mx, acc[r]);
          }
        }
    } else {
      unsigned long long p0 = 0ull, p1 = 0ull;
#pragma unroll
      for (int u = 0; u < 4; u++)
#pragma unroll
        for (int v = 0; v < 4; v++){
          f32x4 z = {0.f, 0.f, 0.f, 0.f};
          f32x4 acc = __builtin_amdgcn_mfma_f32_16x16x32_bf16(a[u], b[v], z, 0, 0, 0);
#pragma unroll
          for (int r = 0; r < 4; r++){
            int idx = (int)((acc[r] - lo) * sc);
            idx = idx < 0 ? 0 : (idx > 15 ? 15 : idx);
            unsigned long long inc = 1ull << ((idx & 7) << 3);
            if (idx < 8) p0 += inc; else p1 += inc;
          }
        }
#pragma unroll
      for (int q = 0; q < 8; q++){
        cnt[q]     += (unsigned)((p0 >> (8 * q)) & 0xffull);
        cnt[8 + q] += (unsigned)((p1 >> (8 * q)) & 0xffull);
      }
    }
  }

  if (PASS == 1){
#pragma unroll
    for (int o = 32; o >= 1; o >>= 1){
      mn = fminf(mn, __shfl_xor(mn, o));
      mx = fmaxf(mx, __shfl_xor(mx, o));
    }
    __shared__ float wmn[4], wmx[4];
    if (l == 0){ wmn[w] = mn; wmx[w] = mx; }
    __syncthreads();
    if (t == 0){
      float bmn = fminf(fminf(wmn[0], wmn[1]), fminf(wmn[2], wmn[3]));
      float bmx = fmaxf(fmaxf(wmx[0], wmx[1]), fmaxf(wmx[2], wmx[3]));
      pmm[blockIdx.x * 2]     = bmn;
      pmm[blockIdx.x * 2 + 1] = bmx;
    }
  } else {
#pragma unroll
    for (int q = 0; q < 16; q++){
#pragma unroll
      for (int o = 32; o >= 1; o >>= 1)
        cnt[q] += (unsigned)__shfl_xor((int)cnt[q], o);
    }
    __shared__ unsigned wcnt[4][16];
    if (l == 0){
#pragma unroll
      for (int q = 0; q < 16; q++) wcnt[w][q] = cnt[q];
    }
    __syncthreads();
    if (t < 16)
      phist[blockIdx.x * 16 + t] = wcnt[0][t] + wcnt[1][t] + wcnt[2][t] + wcnt[3][t];
  }
}

// ---------- reduce per-block min/max partials -> bin edges ----------
__global__ void edges_kernel(const float* __restrict__ pmm, float* __restrict__ edges){
  int t = threadIdx.x;
  float mn = 3.402823466e38f, mx = -3.402823466e38f;
  for (int b = t; b < SIM_BLOCKS; b += 256){
    mn = fminf(mn, pmm[b * 2]);
    mx = fmaxf(mx, pmm[b * 2 + 1]);
  }
#pragma unroll
  for (int o = 32; o >= 1; o >>= 1){
    mn = fminf(mn, __shfl_xor(mn, o));
    mx = fmaxf(mx, __shfl_xor(mx, o));
  }
  __shared__ float wmn[4], wmx[4];
  if ((t & 63) == 0){ wmn[t >> 6] = mn; wmx[t >> 6] = mx; }
  __syncthreads();
  if (t == 0){
    float lo = fminf(fminf(wmn[0], wmn[1]), fminf(wmn[2], wmn[3]));
    float hi = fmaxf(fmaxf(wmx[0], wmx[1]), fmaxf(wmx[2], wmx[3]));
    edges[0] = lo;
    edges[1] = (hi > lo) ? (16.f / (hi - lo)) : 0.f;
  }
}

// ---------- reduce per-block hist partials -> hist[16] ----------
__global__ void hist_reduce(const unsigned* __restrict__ phist, unsigned* __restrict__ hist){
  int t = threadIdx.x;          // 256 threads
  int bin = t & 15, part = t >> 4;
  unsigned s = 0;
  for (int b = part; b < SIM_BLOCKS; b += 16)
    s += phist[b * 16 + bin];
  __shared__ unsigned tmp[256];
  tmp[t] = s;
  __syncthreads();
  if (t < 16){
    unsigned tot = 0;
#pragma unroll
    for (int p = 0; p < 16; p++) tot += tmp[p * 16 + t];
    hist[t] = tot;
  }
}

// ---------- tensor network + hist concat + fc + sigmoid (coalesced tW) ----------
// s[k] = sum_{a,b} e1[a] * tW[(a*32+b)*16 + k] * e2[b].
// 256 thr read tW as 4096 float4 (16/thread, coalesced). For idx = t + 256*i,
// the k-quad q = idx&3 = t&3 is per-thread constant; pair a*32+b = idx>>2.
__global__ void final_kernel(const float* __restrict__ pooled1, const float* __restrict__ pooled2,
                             const float* __restrict__ tW, const float* __restrict__ tWb,
                             const float* __restrict__ tb, const unsigned* __restrict__ hist,
                             const float* __restrict__ fcW, const float* __restrict__ fcb,
                             const float* __restrict__ scW, const float* __restrict__ scb,
                             float* __restrict__ out){
  __shared__ float e1[32], e2[32], v[32], u[16];
  __shared__ float4 accL[256];
  int t = threadIdx.x;
  if (t < 32){ e1[t] = pooled1[t]; e2[t] = pooled2[t]; }
  __syncthreads();
  const float4* tw4 = (const float4*)tW;
  float4 acc = {0.f, 0.f, 0.f, 0.f};
#pragma unroll
  for (int i = 0; i < 16; i++){
    int idx = t + 256 * i;
    int pair = idx >> 2;
    float coef = e1[pair >> 5] * e2[pair & 31];
    float4 w4 = tw4[idx];
    acc.x += coef * w4.x; acc.y += coef * w4.y;
    acc.z += coef * w4.z; acc.w += coef * w4.w;
  }
  accL[t] = acc;
  __syncthreads();
  if (t < 16){
    int q = t >> 2, r = t & 3;
    float s = 0.f;
    for (int j = 0; j < 64; j++){
      float4 a4 = accL[q + 4 * j];
      s += (r == 0) ? a4.x : (r == 1) ? a4.y : (r == 2) ? a4.z : a4.w;
    }
    float blk = 0.f;
    for (int a = 0; a < 32; a++) blk += tWb[t * 64 + a] * e1[a];
    for (int b = 0; b < 32; b++) blk += tWb[t * 64 + 32 + b] * e2[b];
    float rr = s + blk + tb[t];
    v[t] = rr > 0.f ? rr : 0.f;
  }
  __syncthreads();
  if (t == 0){
    float tot = 0.f;
    for (int i = 0; i < 16; i++) tot += (float)hist[i];
    float inv = 1.f / tot;
    for (int i = 0; i < 16; i++) v[16 + i] = (float)hist[i] * inv;
  }
  __syncthreads();
  if (t < 16){
    float s = fcb[t];
    for (int i = 0; i < 32; i++) s += fcW[t * 32 + i] * v[i];
    u[t] = s > 0.f ? s : 0.f;
  }
  __syncthreads();
  if (t == 0){
    float s = scb[0];
    for (int i = 0; i < 16; i++) s += scW[i] * u[i];
    out[0] = 1.f / (1.f + expf(-s));
  }
}

extern "C" void kernel_launch(void* const* d_in, const int* in_sizes, int n_in,
                              void* d_out, int out_size, void* d_ws, size_t ws_size,
                              hipStream_t stream){
  const float* feat[2] = {(const float*)d_in[0], (const float*)d_in[1]};
  const int*   ei[2]   = {(const int*)d_in[2], (const int*)d_in[3]};
  const float* W1  = (const float*)d_in[4];
  const float* b1  = (const float*)d_in[5];
  const float* W2  = (const float*)d_in[6];
  const float* b2  = (const float*)d_in[7];
  const float* W3  = (const float*)d_in[8];
  const float* b3  = (const float*)d_in[9];
  const float* attW = (const float*)d_in[10];
  const float* tW  = (const float*)d_in[11];
  const float* tWb = (const float*)d_in[12];
  const float* tb  = (const float*)d_in[13];
  const float* fcW = (const float*)d_in[14];
  const float* fcb = (const float*)d_in[15];
  const float* scW = (const float*)d_in[16];
  const float* scb = (const float*)d_in[17];

  char* w = (char*)d_ws;
  size_t o = 0;
  auto alloc = [&](size_t bytes)->char*{
    char* p = w + o; o += (bytes + 255) & ~(size_t)255; return p;
  };
  int* deg = (int*)alloc((size_t)2 * NN * 4);
  float* dinv[2]; int* rp[2]; int* cur[2]; int* col[2];
  for (int g = 0; g < 2; g++){
    dinv[g] = (float*)alloc((size_t)NN * 4);
    rp[g]   = (int*)alloc((size_t)(NN + 1) * 4);
    cur[g]  = (int*)alloc((size_t)NN * 4);
    col[g]  = (int*)alloc((size_t)EE * 4);
  }
  float* hbuf = (float*)alloc((size_t)NN * F1d * 4);
  float* abuf = (float*)alloc((size_t)NN * F1d * 4);
  float* af[2] = {(float*)alloc((size_t)NN * F3d * 4), (float*)alloc((size_t)NN * F3d * 4)};
  unsigned short* afb[2] = {(unsigned short*)alloc((size_t)NN * F3d * 2),
                            (unsigned short*)alloc((size_t)NN * F3d * 2)};
  float* pmm = (float*)alloc((size_t)SIM_BLOCKS * 2 * 4);
  unsigned* phist = (unsigned*)alloc((size_t)SIM_BLOCKS * 16 * 4);
  unsigned* hist = (unsigned*)alloc(16 * 4);
  float* smallf = (float*)alloc(1024 * 4);

  float* colsum[2] = {smallf + 0,  smallf + 96};
  float* tg[2]     = {smallf + 32, smallf + 128};
  float* pooled[2] = {smallf + 64, smallf + 160};
  float* edg = smallf + 192;

  init_kernel<<<128, 256, 0, stream>>>(deg, smallf);

  for (int g = 0; g < 2; g++){
    int* degg = deg + g * NN;
    deg_count<<<EE / 256, 256, 0, stream>>>(ei[g], degg);
    scan_kernel<<<1, 1024, 0, stream>>>(degg, rp[g]);
    dinv_cur<<<NN / 256, 256, 0, stream>>>(degg, rp[g], dinv[g], cur[g]);
    fill_kernel<<<EE / 256, 256, 0, stream>>>(ei[g], cur[g], col[g]);

    gemm_hs<DIN, F1d><<<NN / 16, 256, 0, stream>>>(feat[g], W1, dinv[g], hbuf);
    agg_kernel<F1d, true><<<NN / 8, 256, 0, stream>>>(hbuf, rp[g], col[g], dinv[g], b1, abuf);
    gemm_hs<F1d, F2d><<<NN / 16, 256, 0, stream>>>(abuf, W2, dinv[g], hbuf);
    agg_kernel<F2d, true><<<NN / 16, 256, 0, stream>>>(hbuf, rp[g], col[g], dinv[g], b2, abuf);
    gemm_hs<F2d, F3d><<<NN / 16, 256, 0, stream>>>(abuf, W3, dinv[g], hbuf);
    agg_kernel<F3d, false><<<NN / 32, 256, 0, stream>>>(hbuf, rp[g], col[g], dinv[g], b3, af[g]);

    cast_bf16<<<NN * F3d / 1024, 256, 0, stream>>>(af[g], afb[g], NN * F3d);
    colsum_kernel<<<128, 256, 0, stream>>>(af[g], colsum[g]);
    tg_kernel<<<1, 32, 0, stream>>>(colsum[g], attW, tg[g]);
    pool_kernel<<<128, 256, 0, stream>>>(af[g], tg[g], pooled[g]);
  }

  sim_mfma<1><<<SIM_BLOCKS, 256, 0, stream>>>(afb[0], afb[1], edg, pmm, phist);
  edges_kernel<<<1, 256, 0, stream>>>(pmm, edg);
  sim_mfma<2><<<SIM_BLOCKS, 256, 0, stream>>>(afb[0], afb[1], edg, pmm, phist);
  hist_reduce<<<1, 256, 0, stream>>>(phist, hist);

  final_kernel<<<1, 64, 0, stream>>>(pooled[0], pooled[1], tW, tWb, tb, hist,
                                     fcW, fcb, scW, scb, (float*)d_out);
}

// Round 6
// 459.184 us; speedup vs baseline: 27.7034x; 1.2153x over previous
//
#include <hip/hip_runtime.h>
#include <hip/hip_bf16.h>
#include <math.h>

#define NN 16384
#define EE 262144
#define DIN 144
#define F1d 128
#define F2d 64
#define F3d 32

#define SIM_BLOCKS 1024   // persistent sim grid; 4096 waves; each wave: 1 i-strip x 16 j-tiles

typedef __attribute__((ext_vector_type(8))) short bf16x8;
typedef __attribute__((ext_vector_type(4))) float f32x4;

__device__ __forceinline__ unsigned short f2bf(float f){
  unsigned u = __float_as_uint(f);
  unsigned r = (u + 0x7fffu + ((u >> 16) & 1u)) >> 16;   // RNE
  return (unsigned short)r;
}

// ---------- init: zero deg arrays ----------
__global__ void init_kernel(int* __restrict__ deg){
  int t = blockIdx.x * 256 + threadIdx.x;
  if (t < 2 * NN) deg[t] = 0;
}

// ---------- degree count over edge rows (both graphs) ----------
__global__ void deg_count(const int* __restrict__ ei0, const int* __restrict__ ei1,
                          int* __restrict__ deg){
  int g = blockIdx.y;
  const int* ei = g ? ei1 : ei0;
  int e = blockIdx.x * 256 + threadIdx.x;
  if (e < EE) atomicAdd(&deg[g * NN + ei[e]], 1);
}

// ---------- exclusive scan of deg[NN] -> rp[0..NN], one block per graph ----------
__global__ void scan_kernel(const int* __restrict__ degb, int* __restrict__ rpb){
  const int* deg = degb + blockIdx.x * NN;
  int* rp = rpb + blockIdx.x * (NN + 1);
  __shared__ int part[1024];
  int t = threadIdx.x;
  int base = t * 16;
  int v[16]; int s = 0;
#pragma unroll
  for (int i = 0; i < 16; i++){ v[i] = deg[base + i]; s += v[i]; }
  part[t] = s;
  __syncthreads();
  for (int off = 1; off < 1024; off <<= 1){
    int x = (t >= off) ? part[t - off] : 0;
    __syncthreads();
    part[t] += x;
    __syncthreads();
  }
  int excl = part[t] - s;
#pragma unroll
  for (int i = 0; i < 16; i++){ rp[base + i] = excl; excl += v[i]; }
  if (t == 1023) rp[NN] = part[1023];
}

// ---------- dinv = 1/sqrt(deg+1); cursor init (both graphs) ----------
__global__ void dinv_cur(const int* __restrict__ deg, const int* __restrict__ rp,
                         float* __restrict__ dinv, int* __restrict__ cur){
  int g = blockIdx.y;
  int i = blockIdx.x * 256 + threadIdx.x;
  if (i < NN){
    dinv[g * NN + i] = 1.0f / sqrtf((float)(deg[g * NN + i] + 1));
    cur[g * NN + i] = rp[g * (NN + 1) + i];
  }
}

// ---------- CSR fill (both graphs) ----------
__global__ void fill_kernel(const int* __restrict__ ei0, const int* __restrict__ ei1,
                            int* __restrict__ cur, int* __restrict__ col){
  int g = blockIdx.y;
  const int* ei = g ? ei1 : ei0;
  int e = blockIdx.x * 256 + threadIdx.x;
  if (e < EE){
    int r = ei[e];
    int pos = atomicAdd(&cur[g * NN + r], 1);
    col[g * EE + pos] = ei[EE + e];
  }
}

// ---------- hs = dinv[i] * (x @ W)  (both graphs via blockIdx.y) ----------
template<int KD, int FD>
__global__ __launch_bounds__(256) void gemm_hs(const float* __restrict__ X0,
                                               const float* __restrict__ X1,
                                               const float* __restrict__ W,
                                               const float* __restrict__ dinv,
                                               float* __restrict__ HS){
  constexpr int KC = 16;
  constexpr int ROWS = 16;
  constexpr int G = 256 / FD;    // row slots per block
  constexpr int R = ROWS / G;    // rows per thread
  __shared__ float xs[ROWS][KC];
  __shared__ float ws[KC][FD];
  int g = blockIdx.y;
  const float* X = g ? X1 : X0;
  int t = threadIdx.x;
  int f = t % FD;
  int rs = t / FD;
  int row0 = blockIdx.x * ROWS;
  float acc[R];
#pragma unroll
  for (int r = 0; r < R; r++) acc[r] = 0.f;
  for (int k0 = 0; k0 < KD; k0 += KC){
    __syncthreads();
    for (int idx = t; idx < KC * FD; idx += 256){
      int kk = idx / FD, ff = idx % FD;
      ws[kk][ff] = W[(k0 + kk) * FD + ff];
    }
    {
      int rr = t / KC, kk = t % KC;
      xs[rr][kk] = X[(size_t)(row0 + rr) * KD + k0 + kk];
    }
    __syncthreads();
#pragma unroll
    for (int kk = 0; kk < KC; kk++){
      float wv = ws[kk][f];
#pragma unroll
      for (int r = 0; r < R; r++)
        acc[r] += xs[rs * R + r][kk] * wv;
    }
  }
#pragma unroll
  for (int r = 0; r < R; r++){
    int row = row0 + rs * R + r;
    HS[((size_t)g * NN + row) * FD + f] = dinv[g * NN + row] * acc[r];
  }
}

// ---------- out[i] = dinv[i]*(hs[i] + sum_nbr hs[j]) + b  (+relu / +bf16 pack) ------
template<int FD, bool RELU, bool BF16OUT>
__global__ __launch_bounds__(256) void agg_kernel(const float* __restrict__ HS,
                                                  const int* __restrict__ rp,
                                                  const int* __restrict__ col,
                                                  const float* __restrict__ dinv,
                                                  const float* __restrict__ b,
                                                  float* __restrict__ OUT,
                                                  unsigned short* __restrict__ OUTB){
  constexpr int TPN = FD / 4;          // threads per node
  constexpr int NPB = 256 / TPN;       // nodes per block
  int g = blockIdx.y;
  int t = threadIdx.x;
  int f4 = t % TPN;
  int i = blockIdx.x * NPB + t / TPN;
  const float4* HS4 = (const float4*)HS;
  size_t gb = (size_t)g * NN;
  float4 acc = HS4[(gb + i) * TPN + f4];
  int p0 = rp[g * (NN + 1) + i], p1 = rp[g * (NN + 1) + i + 1];
  const int* colg = col + (size_t)g * EE;
  for (int p = p0; p < p1; p++){
    int j = colg[p];
    float4 h = HS4[(gb + j) * TPN + f4];
    acc.x += h.x; acc.y += h.y; acc.z += h.z; acc.w += h.w;
  }
  float di = dinv[g * NN + i];
  float4 bb = ((const float4*)b)[f4];
  float4 o;
  o.x = di * acc.x + bb.x;
  o.y = di * acc.y + bb.y;
  o.z = di * acc.z + bb.z;
  o.w = di * acc.w + bb.w;
  if (RELU){
    o.x = fmaxf(o.x, 0.f); o.y = fmaxf(o.y, 0.f);
    o.z = fmaxf(o.z, 0.f); o.w = fmaxf(o.w, 0.f);
  }
  ((float4*)OUT)[(gb + i) * TPN + f4] = o;
  if (BF16OUT){
    ushort4 ob;
    ob.x = f2bf(o.x); ob.y = f2bf(o.y); ob.z = f2bf(o.z); ob.w = f2bf(o.w);
    ((ushort4*)OUTB)[(gb + i) * TPN + f4] = ob;
  }
}

// ---------- per-block column-sum partials of af (N x 32), atomic-free ----------
__global__ void colsum_kernel(const float* __restrict__ AF, float* __restrict__ cpart){
  __shared__ float s[8][32];
  int g = blockIdx.y;
  int t = threadIdx.x;
  int f = t % 32;
  int slot = t / 32;
  const float* AFg = AF + (size_t)g * NN * 32;
  float a = 0.f;
  for (int i = blockIdx.x * 8 + slot; i < NN; i += gridDim.x * 8)
    a += AFg[(size_t)i * 32 + f];
  s[slot][f] = a;
  __syncthreads();
  if (t < 32){
    float tot = 0.f;
#pragma unroll
    for (int k = 0; k < 8; k++) tot += s[k][f];
    cpart[((size_t)g * 128 + blockIdx.x) * 32 + f] = tot;
  }
}

// ---------- tg = tanh( (colsum/N) @ att_W ), one block per graph ----------
__global__ void tg_kernel(const float* __restrict__ cpart, const float* __restrict__ attW,
                          float* __restrict__ tgb){
  __shared__ float cs[32];
  int g = blockIdx.x;
  int f = threadIdx.x;   // 32 threads
  float s = 0.f;
  for (int b = 0; b < 128; b++)
    s += cpart[((size_t)g * 128 + b) * 32 + f];
  cs[f] = s * (1.f / (float)NN);
  __syncthreads();
  float acc = 0.f;
  for (int k = 0; k < 32; k++)
    acc += cs[k] * attW[k * 32 + f];
  tgb[g * 32 + f] = tanhf(acc);
}

// ---------- pooled partials: af^T @ sigmoid(af @ tg), atomic-free ----------
__global__ void pool_kernel(const float* __restrict__ AF, const float* __restrict__ tgb,
                            float* __restrict__ ppart){
  __shared__ float s[8][32];
  int g = blockIdx.y;
  int t = threadIdx.x;
  int f = t % 32;
  int slot = t / 32;
  const float* AFg = AF + (size_t)g * NN * 32;
  float tgv = tgb[g * 32 + f];
  float acc = 0.f;
  for (int i = blockIdx.x * 8 + slot; i < NN; i += gridDim.x * 8){
    float v = AFg[(size_t)i * 32 + f];
    float d = v * tgv;
#pragma unroll
    for (int o = 16; o >= 1; o >>= 1) d += __shfl_xor(d, o, 32);
    float gate = 1.f / (1.f + expf(-d));
    acc += v * gate;
  }
  s[slot][f] = acc;
  __syncthreads();
  if (t < 32){
    float tot = 0.f;
#pragma unroll
    for (int k = 0; k < 8; k++) tot += s[k][f];
    ppart[((size_t)g * 128 + blockIdx.x) * 32 + f] = tot;
  }
}

// ================= sim = af1 @ af2^T, persistent, ATOMIC-FREE =================
// launch_bounds(256,4): cap 128 VGPR so frags/counters stay in arch VGPRs
// (round-4 lesson: default alloc chose 32 VGPRs -> AGPR churn, 91% VALUBusy).
template<int PASS>
__global__ __launch_bounds__(256, 4) void sim_mfma(const unsigned short* __restrict__ A,
                                                   const unsigned short* __restrict__ B,
                                                   const float* __restrict__ edg,
                                                   float* __restrict__ pmm,
                                                   unsigned* __restrict__ phist){
  int t = threadIdx.x;
  int l = t & 63, w = t >> 6;
  int wave_id = blockIdx.x * 4 + w;
  int istrip = wave_id >> 4;
  int jgrp = wave_id & 15;
  int i0 = istrip * 64;
  int m  = l & 15;
  int k0 = (l >> 4) * 8;

  bf16x8 a[4];
#pragma unroll
  for (int u = 0; u < 4; u++)
    a[u] = *(const bf16x8*)(A + (size_t)(i0 + u * 16 + m) * 32 + k0);

  float mn = 3.402823466e38f, mx = -3.402823466e38f;
  unsigned cnt[16];
#pragma unroll
  for (int q = 0; q < 16; q++) cnt[q] = 0u;
  float off = 0.f, sc = 0.f;
  if (PASS == 2){ off = edg[0]; sc = edg[1]; }

  for (int jj = 0; jj < 16; jj++){
    int j0 = (jgrp * 16 + jj) * 64;
    bf16x8 b[4];
#pragma unroll
    for (int v = 0; v < 4; v++)
      b[v] = *(const bf16x8*)(B + (size_t)(j0 + v * 16 + m) * 32 + k0);

    if (PASS == 1){
#pragma unroll
      for (int u = 0; u < 4; u++)
#pragma unroll
        for (int v = 0; v < 4; v++){
          f32x4 z = {0.f, 0.f, 0.f, 0.f};
          f32x4 acc = __builtin_amdgcn_mfma_f32_16x16x32_bf16(a[u], b[v], z, 0, 0, 0);
          // min3/max3 pairing: 1 VALU per value
          mn = fminf(fminf(acc[0], acc[1]), mn);
          mn = fminf(fminf(acc[2], acc[3]), mn);
          mx = fmaxf(fmaxf(acc[0], acc[1]), mx);
          mx = fmaxf(fmaxf(acc[2], acc[3]), mx);
        }
    } else {
      unsigned long long p0 = 0ull, p1 = 0ull;
#pragma unroll
      for (int u = 0; u < 4; u++)
#pragma unroll
        for (int v = 0; v < 4; v++){
          f32x4 z = {0.f, 0.f, 0.f, 0.f};
          f32x4 acc = __builtin_amdgcn_mfma_f32_16x16x32_bf16(a[u], b[v], z, 0, 0, 0);
#pragma unroll
          for (int r = 0; r < 4; r++){
            // fma + med3 + cvt: 3 VALU to produce idx in [0,15]
            float fi = __builtin_amdgcn_fmed3f(fmaf(acc[r], sc, off), 0.f, 15.f);
            int idx = (int)fi;
            unsigned long long inc = 1ull << ((idx & 7) << 3);
            if (idx < 8) p0 += inc; else p1 += inc;
          }
        }
#pragma unroll
      for (int q = 0; q < 8; q++){
        cnt[q]     += (unsigned)((p0 >> (8 * q)) & 0xffull);
        cnt[8 + q] += (unsigned)((p1 >> (8 * q)) & 0xffull);
      }
    }
  }

  if (PASS == 1){
#pragma unroll
    for (int o = 32; o >= 1; o >>= 1){
      mn = fminf(mn, __shfl_xor(mn, o));
      mx = fmaxf(mx, __shfl_xor(mx, o));
    }
    __shared__ float wmn[4], wmx[4];
    if (l == 0){ wmn[w] = mn; wmx[w] = mx; }
    __syncthreads();
    if (t == 0){
      float bmn = fminf(fminf(wmn[0], wmn[1]), fminf(wmn[2], wmn[3]));
      float bmx = fmaxf(fmaxf(wmx[0], wmx[1]), fmaxf(wmx[2], wmx[3]));
      pmm[blockIdx.x * 2]     = bmn;
      pmm[blockIdx.x * 2 + 1] = bmx;
    }
  } else {
#pragma unroll
    for (int q = 0; q < 16; q++){
#pragma unroll
      for (int o = 32; o >= 1; o >>= 1)
        cnt[q] += (unsigned)__shfl_xor((int)cnt[q], o);
    }
    __shared__ unsigned wcnt[4][16];
    if (l == 0){
#pragma unroll
      for (int q = 0; q < 16; q++) wcnt[w][q] = cnt[q];
    }
    __syncthreads();
    if (t < 16)
      phist[blockIdx.x * 16 + t] = wcnt[0][t] + wcnt[1][t] + wcnt[2][t] + wcnt[3][t];
  }
}

// ---------- reduce per-block min/max partials -> (off, sc) ----------
__global__ void edges_kernel(const float* __restrict__ pmm, float* __restrict__ edg){
  int t = threadIdx.x;
  float mn = 3.402823466e38f, mx = -3.402823466e38f;
  for (int b = t; b < SIM_BLOCKS; b += 256){
    mn = fminf(mn, pmm[b * 2]);
    mx = fmaxf(mx, pmm[b * 2 + 1]);
  }
#pragma unroll
  for (int o = 32; o >= 1; o >>= 1){
    mn = fminf(mn, __shfl_xor(mn, o));
    mx = fmaxf(mx, __shfl_xor(mx, o));
  }
  __shared__ float wmn[4], wmx[4];
  if ((t & 63) == 0){ wmn[t >> 6] = mn; wmx[t >> 6] = mx; }
  __syncthreads();
  if (t == 0){
    float lo = fminf(fminf(wmn[0], wmn[1]), fminf(wmn[2], wmn[3]));
    float hi = fmaxf(fmaxf(wmx[0], wmx[1]), fmaxf(wmx[2], wmx[3]));
    float sc = (hi > lo) ? (16.f / (hi - lo)) : 0.f;
    edg[0] = -lo * sc;   // off
    edg[1] = sc;
  }
}

// ---------- final: pooled reduce + hist reduce + tnet + fc + sigmoid ----------
__global__ void final_kernel(const float* __restrict__ ppart, const unsigned* __restrict__ phist,
                             const float* __restrict__ tW, const float* __restrict__ tWb,
                             const float* __restrict__ tb,
                             const float* __restrict__ fcW, const float* __restrict__ fcb,
                             const float* __restrict__ scW, const float* __restrict__ scb,
                             float* __restrict__ out){
  __shared__ float e[2][32], v32[32], uu[16], hn[16];
  __shared__ unsigned htmp[256];
  __shared__ float4 accL[256];
  int t = threadIdx.x;  // 256

  if (t < 64){
    int g = t >> 5, f = t & 31;
    float s = 0.f;
    for (int b = 0; b < 128; b++)
      s += ppart[((size_t)g * 128 + b) * 32 + f];
    e[g][f] = s;
  }
  {
    int bin = t & 15;
    unsigned hs = 0;
    for (int b = t >> 4; b < SIM_BLOCKS; b += 16)
      hs += phist[b * 16 + bin];
    htmp[t] = hs;
  }
  __syncthreads();

  if (t < 16){
    unsigned c = 0;
#pragma unroll
    for (int p = 0; p < 16; p++) c += htmp[p * 16 + t];
    hn[t] = (float)c;
  }

  // tnet contraction: s[k] = sum_{a,b} e1[a]*tW[(a*32+b)*16+k]*e2[b], coalesced
  const float4* tw4 = (const float4*)tW;
  float4 acc = {0.f, 0.f, 0.f, 0.f};
#pragma unroll
  for (int i = 0; i < 16; i++){
    int idx = t + 256 * i;
    int pair = idx >> 2;
    float coef = e[0][pair >> 5] * e[1][pair & 31];
    float4 w4 = tw4[idx];
    acc.x += coef * w4.x; acc.y += coef * w4.y;
    acc.z += coef * w4.z; acc.w += coef * w4.w;
  }
  accL[t] = acc;
  __syncthreads();

  if (t < 16){
    int q = t >> 2, r = t & 3;
    float s = 0.f;
    for (int j = 0; j < 64; j++){
      float4 a4 = accL[q + 4 * j];
      s += (r == 0) ? a4.x : (r == 1) ? a4.y : (r == 2) ? a4.z : a4.w;
    }
    float blk = 0.f;
    for (int a = 0; a < 32; a++) blk += tWb[t * 64 + a] * e[0][a];
    for (int b = 0; b < 32; b++) blk += tWb[t * 64 + 32 + b] * e[1][b];
    float rr = s + blk + tb[t];
    v32[t] = rr > 0.f ? rr : 0.f;
  }
  __syncthreads();

  if (t < 16){
    float tot = 0.f;
#pragma unroll
    for (int i = 0; i < 16; i++) tot += hn[i];
    float inv = 1.f / tot;
    float s = fcb[t];
    for (int i = 0; i < 16; i++) s += fcW[t * 32 + i] * v32[i];
    for (int i = 0; i < 16; i++) s += fcW[t * 32 + 16 + i] * (hn[i] * inv);
    uu[t] = s > 0.f ? s : 0.f;
  }
  __syncthreads();
  if (t == 0){
    float s = scb[0];
    for (int i = 0; i < 16; i++) s += scW[i] * uu[i];
    out[0] = 1.f / (1.f + expf(-s));
  }
}

extern "C" void kernel_launch(void* const* d_in, const int* in_sizes, int n_in,
                              void* d_out, int out_size, void* d_ws, size_t ws_size,
                              hipStream_t stream){
  const float* feat0 = (const float*)d_in[0];
  const float* feat1 = (const float*)d_in[1];
  const int*   ei0   = (const int*)d_in[2];
  const int*   ei1   = (const int*)d_in[3];
  const float* W1  = (const float*)d_in[4];
  const float* b1  = (const float*)d_in[5];
  const float* W2  = (const float*)d_in[6];
  const float* b2  = (const float*)d_in[7];
  const float* W3  = (const float*)d_in[8];
  const float* b3  = (const float*)d_in[9];
  const float* attW = (const float*)d_in[10];
  const float* tW  = (const float*)d_in[11];
  const float* tWb = (const float*)d_in[12];
  const float* tb  = (const float*)d_in[13];
  const float* fcW = (const float*)d_in[14];
  const float* fcb = (const float*)d_in[15];
  const float* scW = (const float*)d_in[16];
  const float* scb = (const float*)d_in[17];

  char* w = (char*)d_ws;
  size_t o = 0;
  auto alloc = [&](size_t bytes)->char*{
    char* p = w + o; o += (bytes + 255) & ~(size_t)255; return p;
  };
  int* deg   = (int*)alloc((size_t)2 * NN * 4);
  int* rp    = (int*)alloc((size_t)2 * (NN + 1) * 4);
  int* cur   = (int*)alloc((size_t)2 * NN * 4);
  int* col   = (int*)alloc((size_t)2 * EE * 4);
  float* dinv = (float*)alloc((size_t)2 * NN * 4);
  float* hbuf = (float*)alloc((size_t)2 * NN * F1d * 4);
  float* abuf = (float*)alloc((size_t)2 * NN * F1d * 4);
  float* af   = (float*)alloc((size_t)2 * NN * F3d * 4);
  unsigned short* afb = (unsigned short*)alloc((size_t)2 * NN * F3d * 2);
  float* cpart = (float*)alloc((size_t)2 * 128 * 32 * 4);
  float* ppart = (float*)alloc((size_t)2 * 128 * 32 * 4);
  float* pmm   = (float*)alloc((size_t)SIM_BLOCKS * 2 * 4);
  unsigned* phist = (unsigned*)alloc((size_t)SIM_BLOCKS * 16 * 4);
  float* smallf = (float*)alloc(256 * 4);
  float* tgb = smallf;        // [2][32]
  float* edg = smallf + 64;   // off, sc

  init_kernel<<<128, 256, 0, stream>>>(deg);
  deg_count<<<dim3(EE / 256, 2), 256, 0, stream>>>(ei0, ei1, deg);
  scan_kernel<<<2, 1024, 0, stream>>>(deg, rp);
  dinv_cur<<<dim3(NN / 256, 2), 256, 0, stream>>>(deg, rp, dinv, cur);
  fill_kernel<<<dim3(EE / 256, 2), 256, 0, stream>>>(ei0, ei1, cur, col);

  gemm_hs<DIN, F1d><<<dim3(NN / 16, 2), 256, 0, stream>>>(feat0, feat1, W1, dinv, hbuf);
  agg_kernel<F1d, true, false><<<dim3(NN / 8, 2), 256, 0, stream>>>(hbuf, rp, col, dinv, b1, abuf, nullptr);
  gemm_hs<F1d, F2d><<<dim3(NN / 16, 2), 256, 0, stream>>>(abuf, abuf + (size_t)NN * F1d, W2, dinv, hbuf);
  agg_kernel<F2d, true, false><<<dim3(NN / 16, 2), 256, 0, stream>>>(hbuf, rp, col, dinv, b2, abuf, nullptr);
  gemm_hs<F2d, F3d><<<dim3(NN / 16, 2), 256, 0, stream>>>(abuf, abuf + (size_t)NN * F2d, W3, dinv, hbuf);
  agg_kernel<F3d, false, true><<<dim3(NN / 32, 2), 256, 0, stream>>>(hbuf, rp, col, dinv, b3, af, afb);

  colsum_kernel<<<dim3(128, 2), 256, 0, stream>>>(af, cpart);
  tg_kernel<<<2, 32, 0, stream>>>(cpart, attW, tgb);
  pool_kernel<<<dim3(128, 2), 256, 0, stream>>>(af, tgb, ppart);

  const unsigned short* afb0 = afb;
  const unsigned short* afb1 = afb + (size_t)NN * F3d;
  sim_mfma<1><<<SIM_BLOCKS, 256, 0, stream>>>(afb0, afb1, edg, pmm, phist);
  edges_kernel<<<1, 256, 0, stream>>>(pmm, edg);
  sim_mfma<2><<<SIM_BLOCKS, 256, 0, stream>>>(afb0, afb1, edg, pmm, phist);

  final_kernel<<<1, 256, 0, stream>>>(ppart, phist, tW, tWb, tb,
                                      fcW, fcb, scW, scb, (float*)d_out);
}

// Round 7
// 413.259 us; speedup vs baseline: 30.7820x; 1.1111x over previous
//
#include <hip/hip_runtime.h>
#include <hip/hip_bf16.h>
#include <math.h>

#define NN 16384
#define EE 262144
#define DIN 144
#define F1d 128
#define F2d 64
#define F3d 32

#define SIM_BLOCKS 1024   // persistent sim grid; 4096 waves; each wave: 1 i-strip x 16 j-tiles

typedef __attribute__((ext_vector_type(8))) short bf16x8;
typedef __attribute__((ext_vector_type(4))) float f32x4;

__device__ __forceinline__ unsigned short f2bf(float f){
  unsigned u = __float_as_uint(f);
  unsigned r = (u + 0x7fffu + ((u >> 16) & 1u)) >> 16;   // RNE
  return (unsigned short)r;
}

// ---------- init: zero deg arrays ----------
__global__ void init_kernel(int* __restrict__ deg){
  int t = blockIdx.x * 256 + threadIdx.x;
  if (t < 2 * NN) deg[t] = 0;
}

// ---------- degree count over edge rows (both graphs) ----------
__global__ void deg_count(const int* __restrict__ ei0, const int* __restrict__ ei1,
                          int* __restrict__ deg){
  int g = blockIdx.y;
  const int* ei = g ? ei1 : ei0;
  int e = blockIdx.x * 256 + threadIdx.x;
  if (e < EE) atomicAdd(&deg[g * NN + ei[e]], 1);
}

// ---------- exclusive scan of deg[NN] -> rp[0..NN], one block per graph ----------
__global__ void scan_kernel(const int* __restrict__ degb, int* __restrict__ rpb){
  const int* deg = degb + blockIdx.x * NN;
  int* rp = rpb + blockIdx.x * (NN + 1);
  __shared__ int part[1024];
  int t = threadIdx.x;
  int base = t * 16;
  int v[16]; int s = 0;
#pragma unroll
  for (int i = 0; i < 16; i++){ v[i] = deg[base + i]; s += v[i]; }
  part[t] = s;
  __syncthreads();
  for (int off = 1; off < 1024; off <<= 1){
    int x = (t >= off) ? part[t - off] : 0;
    __syncthreads();
    part[t] += x;
    __syncthreads();
  }
  int excl = part[t] - s;
#pragma unroll
  for (int i = 0; i < 16; i++){ rp[base + i] = excl; excl += v[i]; }
  if (t == 1023) rp[NN] = part[1023];
}

// ---------- dinv = 1/sqrt(deg+1); cursor init (both graphs) ----------
__global__ void dinv_cur(const int* __restrict__ deg, const int* __restrict__ rp,
                         float* __restrict__ dinv, int* __restrict__ cur){
  int g = blockIdx.y;
  int i = blockIdx.x * 256 + threadIdx.x;
  if (i < NN){
    dinv[g * NN + i] = 1.0f / sqrtf((float)(deg[g * NN + i] + 1));
    cur[g * NN + i] = rp[g * (NN + 1) + i];
  }
}

// ---------- CSR fill (both graphs) ----------
__global__ void fill_kernel(const int* __restrict__ ei0, const int* __restrict__ ei1,
                            int* __restrict__ cur, int* __restrict__ col){
  int g = blockIdx.y;
  const int* ei = g ? ei1 : ei0;
  int e = blockIdx.x * 256 + threadIdx.x;
  if (e < EE){
    int r = ei[e];
    int pos = atomicAdd(&cur[g * NN + r], 1);
    col[g * EE + pos] = ei[EE + e];
  }
}

// ---------- hs = dinv[i] * (x @ W)  (both graphs via blockIdx.y) ----------
template<int KD, int FD>
__global__ __launch_bounds__(256) void gemm_hs(const float* __restrict__ X0,
                                               const float* __restrict__ X1,
                                               const float* __restrict__ W,
                                               const float* __restrict__ dinv,
                                               float* __restrict__ HS){
  constexpr int KC = 16;
  constexpr int ROWS = 16;
  constexpr int G = 256 / FD;    // row slots per block
  constexpr int R = ROWS / G;    // rows per thread
  __shared__ float xs[ROWS][KC];
  __shared__ float ws[KC][FD];
  int g = blockIdx.y;
  const float* X = g ? X1 : X0;
  int t = threadIdx.x;
  int f = t % FD;
  int rs = t / FD;
  int row0 = blockIdx.x * ROWS;
  float acc[R];
#pragma unroll
  for (int r = 0; r < R; r++) acc[r] = 0.f;
  for (int k0 = 0; k0 < KD; k0 += KC){
    __syncthreads();
    for (int idx = t; idx < KC * FD; idx += 256){
      int kk = idx / FD, ff = idx % FD;
      ws[kk][ff] = W[(k0 + kk) * FD + ff];
    }
    {
      int rr = t / KC, kk = t % KC;
      xs[rr][kk] = X[(size_t)(row0 + rr) * KD + k0 + kk];
    }
    __syncthreads();
#pragma unroll
    for (int kk = 0; kk < KC; kk++){
      float wv = ws[kk][f];
#pragma unroll
      for (int r = 0; r < R; r++)
        acc[r] += xs[rs * R + r][kk] * wv;
    }
  }
#pragma unroll
  for (int r = 0; r < R; r++){
    int row = row0 + rs * R + r;
    HS[((size_t)g * NN + row) * FD + f] = dinv[g * NN + row] * acc[r];
  }
}

// ---------- out[i] = dinv[i]*(hs[i] + sum_nbr hs[j]) + b  (+relu / +bf16 pack) ------
template<int FD, bool RELU, bool BF16OUT>
__global__ __launch_bounds__(256) void agg_kernel(const float* __restrict__ HS,
                                                  const int* __restrict__ rp,
                                                  const int* __restrict__ col,
                                                  const float* __restrict__ dinv,
                                                  const float* __restrict__ b,
                                                  float* __restrict__ OUT,
                                                  unsigned short* __restrict__ OUTB){
  constexpr int TPN = FD / 4;          // threads per node
  constexpr int NPB = 256 / TPN;       // nodes per block
  int g = blockIdx.y;
  int t = threadIdx.x;
  int f4 = t % TPN;
  int i = blockIdx.x * NPB + t / TPN;
  const float4* HS4 = (const float4*)HS;
  size_t gb = (size_t)g * NN;
  float4 acc = HS4[(gb + i) * TPN + f4];
  int p0 = rp[g * (NN + 1) + i], p1 = rp[g * (NN + 1) + i + 1];
  const int* colg = col + (size_t)g * EE;
  for (int p = p0; p < p1; p++){
    int j = colg[p];
    float4 h = HS4[(gb + j) * TPN + f4];
    acc.x += h.x; acc.y += h.y; acc.z += h.z; acc.w += h.w;
  }
  float di = dinv[g * NN + i];
  float4 bb = ((const float4*)b)[f4];
  float4 o;
  o.x = di * acc.x + bb.x;
  o.y = di * acc.y + bb.y;
  o.z = di * acc.z + bb.z;
  o.w = di * acc.w + bb.w;
  if (RELU){
    o.x = fmaxf(o.x, 0.f); o.y = fmaxf(o.y, 0.f);
    o.z = fmaxf(o.z, 0.f); o.w = fmaxf(o.w, 0.f);
  }
  ((float4*)OUT)[(gb + i) * TPN + f4] = o;
  if (BF16OUT){
    ushort4 ob;
    ob.x = f2bf(o.x); ob.y = f2bf(o.y); ob.z = f2bf(o.z); ob.w = f2bf(o.w);
    ((ushort4*)OUTB)[(gb + i) * TPN + f4] = ob;
  }
}

// ---------- per-block column-sum partials of af (N x 32), atomic-free ----------
__global__ void colsum_kernel(const float* __restrict__ AF, float* __restrict__ cpart){
  __shared__ float s[8][32];
  int g = blockIdx.y;
  int t = threadIdx.x;
  int f = t % 32;
  int slot = t / 32;
  const float* AFg = AF + (size_t)g * NN * 32;
  float a = 0.f;
  for (int i = blockIdx.x * 8 + slot; i < NN; i += gridDim.x * 8)
    a += AFg[(size_t)i * 32 + f];
  s[slot][f] = a;
  __syncthreads();
  if (t < 32){
    float tot = 0.f;
#pragma unroll
    for (int k = 0; k < 8; k++) tot += s[k][f];
    cpart[((size_t)g * 128 + blockIdx.x) * 32 + f] = tot;
  }
}

// ---------- tg = tanh( (colsum/N) @ att_W ), one block per graph ----------
__global__ void tg_kernel(const float* __restrict__ cpart, const float* __restrict__ attW,
                          float* __restrict__ tgb){
  __shared__ float cs[32];
  int g = blockIdx.x;
  int f = threadIdx.x;   // 32 threads
  float s = 0.f;
  for (int b = 0; b < 128; b++)
    s += cpart[((size_t)g * 128 + b) * 32 + f];
  cs[f] = s * (1.f / (float)NN);
  __syncthreads();
  float acc = 0.f;
  for (int k = 0; k < 32; k++)
    acc += cs[k] * attW[k * 32 + f];
  tgb[g * 32 + f] = tanhf(acc);
}

// ---------- pooled partials: af^T @ sigmoid(af @ tg), atomic-free ----------
__global__ void pool_kernel(const float* __restrict__ AF, const float* __restrict__ tgb,
                            float* __restrict__ ppart){
  __shared__ float s[8][32];
  int g = blockIdx.y;
  int t = threadIdx.x;
  int f = t % 32;
  int slot = t / 32;
  const float* AFg = AF + (size_t)g * NN * 32;
  float tgv = tgb[g * 32 + f];
  float acc = 0.f;
  for (int i = blockIdx.x * 8 + slot; i < NN; i += gridDim.x * 8){
    float v = AFg[(size_t)i * 32 + f];
    float d = v * tgv;
#pragma unroll
    for (int o = 16; o >= 1; o >>= 1) d += __shfl_xor(d, o, 32);
    float gate = 1.f / (1.f + expf(-d));
    acc += v * gate;
  }
  s[slot][f] = acc;
  __syncthreads();
  if (t < 32){
    float tot = 0.f;
#pragma unroll
    for (int k = 0; k < 8; k++) tot += s[k][f];
    ppart[((size_t)g * 128 + blockIdx.x) * 32 + f] = tot;
  }
}

// ================= sim = af1 @ af2^T, persistent, ATOMIC-FREE =================
// amdgpu_waves_per_eu(4,4): min=max=4 waves/EU -> 128-VGPR budget the allocator
// will actually use (round-6 lesson: __launch_bounds__(256,4) only sets the MIN,
// compiler still targeted 8 waves/EU -> 36 VGPRs -> AGPR-scratch churn = 88% VALU).
// Pass 2 bins via per-lane LDS slots: one ds_add_u32 per value, slot [w][bin][l]
// owned by exactly one thread (no contention; lane-stride-4B = 2-way bank
// aliasing = free per m136).
template<int PASS>
__global__ __attribute__((amdgpu_flat_work_group_size(256, 256), amdgpu_waves_per_eu(4, 4)))
void sim_mfma(const unsigned short* __restrict__ A,
              const unsigned short* __restrict__ B,
              const float* __restrict__ edg,
              float* __restrict__ pmm,
              unsigned* __restrict__ phist){
  __shared__ unsigned lh[4][16][64];      // 16 KB; used in PASS 2
  __shared__ unsigned red[16][16];
  int t = threadIdx.x;
  int l = t & 63, w = t >> 6;
  int wave_id = blockIdx.x * 4 + w;
  int istrip = wave_id >> 4;
  int jgrp = wave_id & 15;
  int i0 = istrip * 64;
  int m  = l & 15;
  int k0 = (l >> 4) * 8;

  unsigned* myslot = &lh[w][0][l];        // stride 64 u32 between bins
  if (PASS == 2){
#pragma unroll
    for (int q = 0; q < 16; q++) myslot[q * 64] = 0u;
    // no barrier needed: each slot is read/written by its owner only until the end
  }

  bf16x8 a[4];
#pragma unroll
  for (int u = 0; u < 4; u++)
    a[u] = *(const bf16x8*)(A + (size_t)(i0 + u * 16 + m) * 32 + k0);

  float mn = 3.402823466e38f, mx = -3.402823466e38f;
  float off = 0.f, sc = 0.f;
  if (PASS == 2){ off = edg[0]; sc = edg[1]; }

  for (int jj = 0; jj < 16; jj++){
    int j0 = (jgrp * 16 + jj) * 64;
    bf16x8 b[4];
#pragma unroll
    for (int v = 0; v < 4; v++)
      b[v] = *(const bf16x8*)(B + (size_t)(j0 + v * 16 + m) * 32 + k0);

    if (PASS == 1){
#pragma unroll
      for (int u = 0; u < 4; u++)
#pragma unroll
        for (int v = 0; v < 4; v++){
          f32x4 z = {0.f, 0.f, 0.f, 0.f};
          f32x4 acc = __builtin_amdgcn_mfma_f32_16x16x32_bf16(a[u], b[v], z, 0, 0, 0);
          mn = fminf(fminf(acc[0], acc[1]), mn);   // v_min3
          mn = fminf(fminf(acc[2], acc[3]), mn);
          mx = fmaxf(fmaxf(acc[0], acc[1]), mx);   // v_max3
          mx = fmaxf(fmaxf(acc[2], acc[3]), mx);
        }
    } else {
#pragma unroll
      for (int u = 0; u < 4; u++)
#pragma unroll
        for (int v = 0; v < 4; v++){
          f32x4 z = {0.f, 0.f, 0.f, 0.f};
          f32x4 acc = __builtin_amdgcn_mfma_f32_16x16x32_bf16(a[u], b[v], z, 0, 0, 0);
#pragma unroll
          for (int r = 0; r < 4; r++){
            // fma + med3 + cvt + lshl_add + ds_add : ~5 VALU + 1 DS per value
            int idx = (int)__builtin_amdgcn_fmed3f(fmaf(acc[r], sc, off), 0.f, 15.f);
            atomicAdd(&myslot[idx * 64], 1u);
          }
        }
    }
  }

  if (PASS == 1){
#pragma unroll
    for (int o = 32; o >= 1; o >>= 1){
      mn = fminf(mn, __shfl_xor(mn, o));
      mx = fmaxf(mx, __shfl_xor(mx, o));
    }
    __shared__ float wmn[4], wmx[4];
    if (l == 0){ wmn[w] = mn; wmx[w] = mx; }
    __syncthreads();
    if (t == 0){
      float bmn = fminf(fminf(wmn[0], wmn[1]), fminf(wmn[2], wmn[3]));
      float bmx = fmaxf(fmaxf(wmx[0], wmx[1]), fmaxf(wmx[2], wmx[3]));
      pmm[blockIdx.x * 2]     = bmn;
      pmm[blockIdx.x * 2 + 1] = bmx;
    }
  } else {
    __syncthreads();
    // cross-thread reduction of lh: thread t sums bin=t&15 over 4 waves x 4 lanes
    int bin = t & 15, part = t >> 4;
    unsigned s = 0;
#pragma unroll
    for (int ww = 0; ww < 4; ww++)
#pragma unroll
      for (int lc = 0; lc < 4; lc++)
        s += lh[ww][bin][part * 4 + lc];
    red[part][bin] = s;
    __syncthreads();
    if (t < 16){
      unsigned tot = 0;
#pragma unroll
      for (int p = 0; p < 16; p++) tot += red[p][t];
      phist[blockIdx.x * 16 + t] = tot;
    }
  }
}

// ---------- reduce per-block min/max partials -> (off, sc) ----------
__global__ void edges_kernel(const float* __restrict__ pmm, float* __restrict__ edg){
  int t = threadIdx.x;
  float mn = 3.402823466e38f, mx = -3.402823466e38f;
  for (int b = t; b < SIM_BLOCKS; b += 256){
    mn = fminf(mn, pmm[b * 2]);
    mx = fmaxf(mx, pmm[b * 2 + 1]);
  }
#pragma unroll
  for (int o = 32; o >= 1; o >>= 1){
    mn = fminf(mn, __shfl_xor(mn, o));
    mx = fmaxf(mx, __shfl_xor(mx, o));
  }
  __shared__ float wmn[4], wmx[4];
  if ((t & 63) == 0){ wmn[t >> 6] = mn; wmx[t >> 6] = mx; }
  __syncthreads();
  if (t == 0){
    float lo = fminf(fminf(wmn[0], wmn[1]), fminf(wmn[2], wmn[3]));
    float hi = fmaxf(fmaxf(wmx[0], wmx[1]), fmaxf(wmx[2], wmx[3]));
    float sc = (hi > lo) ? (16.f / (hi - lo)) : 0.f;
    edg[0] = -lo * sc;   // off
    edg[1] = sc;
  }
}

// ---------- final: pooled reduce + hist reduce + tnet + fc + sigmoid ----------
__global__ void final_kernel(const float* __restrict__ ppart, const unsigned* __restrict__ phist,
                             const float* __restrict__ tW, const float* __restrict__ tWb,
                             const float* __restrict__ tb,
                             const float* __restrict__ fcW, const float* __restrict__ fcb,
                             const float* __restrict__ scW, const float* __restrict__ scb,
                             float* __restrict__ out){
  __shared__ float e[2][32], v32[32], uu[16], hn[16];
  __shared__ unsigned htmp[256];
  __shared__ float4 accL[256];
  int t = threadIdx.x;  // 256

  if (t < 64){
    int g = t >> 5, f = t & 31;
    float s = 0.f;
    for (int b = 0; b < 128; b++)
      s += ppart[((size_t)g * 128 + b) * 32 + f];
    e[g][f] = s;
  }
  {
    int bin = t & 15;
    unsigned hs = 0;
    for (int b = t >> 4; b < SIM_BLOCKS; b += 16)
      hs += phist[b * 16 + bin];
    htmp[t] = hs;
  }
  __syncthreads();

  if (t < 16){
    unsigned c = 0;
#pragma unroll
    for (int p = 0; p < 16; p++) c += htmp[p * 16 + t];
    hn[t] = (float)c;
  }

  // tnet contraction: s[k] = sum_{a,b} e1[a]*tW[(a*32+b)*16+k]*e2[b], coalesced
  const float4* tw4 = (const float4*)tW;
  float4 acc = {0.f, 0.f, 0.f, 0.f};
#pragma unroll
  for (int i = 0; i < 16; i++){
    int idx = t + 256 * i;
    int pair = idx >> 2;
    float coef = e[0][pair >> 5] * e[1][pair & 31];
    float4 w4 = tw4[idx];
    acc.x += coef * w4.x; acc.y += coef * w4.y;
    acc.z += coef * w4.z; acc.w += coef * w4.w;
  }
  accL[t] = acc;
  __syncthreads();

  if (t < 16){
    int q = t >> 2, r = t & 3;
    float s = 0.f;
    for (int j = 0; j < 64; j++){
      float4 a4 = accL[q + 4 * j];
      s += (r == 0) ? a4.x : (r == 1) ? a4.y : (r == 2) ? a4.z : a4.w;
    }
    float blk = 0.f;
    for (int a = 0; a < 32; a++) blk += tWb[t * 64 + a] * e[0][a];
    for (int b = 0; b < 32; b++) blk += tWb[t * 64 + 32 + b] * e[1][b];
    float rr = s + blk + tb[t];
    v32[t] = rr > 0.f ? rr : 0.f;
  }
  __syncthreads();

  if (t < 16){
    float tot = 0.f;
#pragma unroll
    for (int i = 0; i < 16; i++) tot += hn[i];
    float inv = 1.f / tot;
    float s = fcb[t];
    for (int i = 0; i < 16; i++) s += fcW[t * 32 + i] * v32[i];
    for (int i = 0; i < 16; i++) s += fcW[t * 32 + 16 + i] * (hn[i] * inv);
    uu[t] = s > 0.f ? s : 0.f;
  }
  __syncthreads();
  if (t == 0){
    float s = scb[0];
    for (int i = 0; i < 16; i++) s += scW[i] * uu[i];
    out[0] = 1.f / (1.f + expf(-s));
  }
}

extern "C" void kernel_launch(void* const* d_in, const int* in_sizes, int n_in,
                              void* d_out, int out_size, void* d_ws, size_t ws_size,
                              hipStream_t stream){
  const float* feat0 = (const float*)d_in[0];
  const float* feat1 = (const float*)d_in[1];
  const int*   ei0   = (const int*)d_in[2];
  const int*   ei1   = (const int*)d_in[3];
  const float* W1  = (const float*)d_in[4];
  const float* b1  = (const float*)d_in[5];
  const float* W2  = (const float*)d_in[6];
  const float* b2  = (const float*)d_in[7];
  const float* W3  = (const float*)d_in[8];
  const float* b3  = (const float*)d_in[9];
  const float* attW = (const float*)d_in[10];
  const float* tW  = (const float*)d_in[11];
  const float* tWb = (const float*)d_in[12];
  const float* tb  = (const float*)d_in[13];
  const float* fcW = (const float*)d_in[14];
  const float* fcb = (const float*)d_in[15];
  const float* scW = (const float*)d_in[16];
  const float* scb = (const float*)d_in[17];

  char* w = (char*)d_ws;
  size_t o = 0;
  auto alloc = [&](size_t bytes)->char*{
    char* p = w + o; o += (bytes + 255) & ~(size_t)255; return p;
  };
  int* deg   = (int*)alloc((size_t)2 * NN * 4);
  int* rp    = (int*)alloc((size_t)2 * (NN + 1) * 4);
  int* cur   = (int*)alloc((size_t)2 * NN * 4);
  int* col   = (int*)alloc((size_t)2 * EE * 4);
  float* dinv = (float*)alloc((size_t)2 * NN * 4);
  float* hbuf = (float*)alloc((size_t)2 * NN * F1d * 4);
  float* abuf = (float*)alloc((size_t)2 * NN * F1d * 4);
  float* af   = (float*)alloc((size_t)2 * NN * F3d * 4);
  unsigned short* afb = (unsigned short*)alloc((size_t)2 * NN * F3d * 2);
  float* cpart = (float*)alloc((size_t)2 * 128 * 32 * 4);
  float* ppart = (float*)alloc((size_t)2 * 128 * 32 * 4);
  float* pmm   = (float*)alloc((size_t)SIM_BLOCKS * 2 * 4);
  unsigned* phist = (unsigned*)alloc((size_t)SIM_BLOCKS * 16 * 4);
  float* smallf = (float*)alloc(256 * 4);
  float* tgb = smallf;        // [2][32]
  float* edg = smallf + 64;   // off, sc

  init_kernel<<<128, 256, 0, stream>>>(deg);
  deg_count<<<dim3(EE / 256, 2), 256, 0, stream>>>(ei0, ei1, deg);
  scan_kernel<<<2, 1024, 0, stream>>>(deg, rp);
  dinv_cur<<<dim3(NN / 256, 2), 256, 0, stream>>>(deg, rp, dinv, cur);
  fill_kernel<<<dim3(EE / 256, 2), 256, 0, stream>>>(ei0, ei1, cur, col);

  gemm_hs<DIN, F1d><<<dim3(NN / 16, 2), 256, 0, stream>>>(feat0, feat1, W1, dinv, hbuf);
  agg_kernel<F1d, true, false><<<dim3(NN / 8, 2), 256, 0, stream>>>(hbuf, rp, col, dinv, b1, abuf, nullptr);
  gemm_hs<F1d, F2d><<<dim3(NN / 16, 2), 256, 0, stream>>>(abuf, abuf + (size_t)NN * F1d, W2, dinv, hbuf);
  agg_kernel<F2d, true, false><<<dim3(NN / 16, 2), 256, 0, stream>>>(hbuf, rp, col, dinv, b2, abuf, nullptr);
  gemm_hs<F2d, F3d><<<dim3(NN / 16, 2), 256, 0, stream>>>(abuf, abuf + (size_t)NN * F2d, W3, dinv, hbuf);
  agg_kernel<F3d, false, true><<<dim3(NN / 32, 2), 256, 0, stream>>>(hbuf, rp, col, dinv, b3, af, afb);

  colsum_kernel<<<dim3(128, 2), 256, 0, stream>>>(af, cpart);
  tg_kernel<<<2, 32, 0, stream>>>(cpart, attW, tgb);
  pool_kernel<<<dim3(128, 2), 256, 0, stream>>>(af, tgb, ppart);

  const unsigned short* afb0 = afb;
  const unsigned short* afb1 = afb + (size_t)NN * F3d;
  sim_mfma<1><<<SIM_BLOCKS, 256, 0, stream>>>(afb0, afb1, edg, pmm, phist);
  edges_kernel<<<1, 256, 0, stream>>>(pmm, edg);
  sim_mfma<2><<<SIM_BLOCKS, 256, 0, stream>>>(afb0, afb1, edg, pmm, phist);

  final_kernel<<<1, 256, 0, stream>>>(ppart, phist, tW, tWb, tb,
                                      fcW, fcb, scW, scb, (float*)d_out);
}

// Round 8
// 346.719 us; speedup vs baseline: 36.6895x; 1.1919x over previous
//
#include <hip/hip_runtime.h>
#include <hip/hip_bf16.h>
#include <math.h>

#define NN 16384
#define EE 262144
#define DIN 144
#define F1d 128
#define F2d 64
#define F3d 32

#define SIM_BLOCKS 1024   // persistent sim grid; 4096 waves; each wave: 1 i-strip x 16 j-tiles

typedef __attribute__((ext_vector_type(8))) short bf16x8;
typedef __attribute__((ext_vector_type(4))) float f32x4;

__device__ __forceinline__ unsigned short f2bf(float f){
  unsigned u = __float_as_uint(f);
  unsigned r = (u + 0x7fffu + ((u >> 16) & 1u)) >> 16;   // RNE
  return (unsigned short)r;
}
__device__ __forceinline__ float bf2f(unsigned short u){
  return __uint_as_float(((unsigned)u) << 16);
}

// ---------- init: zero deg arrays ----------
__global__ void init_kernel(int* __restrict__ deg){
  int t = blockIdx.x * 256 + threadIdx.x;
  if (t < 2 * NN) deg[t] = 0;
}

// ---------- degree count over edge rows (both graphs) ----------
__global__ void deg_count(const int* __restrict__ ei0, const int* __restrict__ ei1,
                          int* __restrict__ deg){
  int g = blockIdx.y;
  const int* ei = g ? ei1 : ei0;
  int e = blockIdx.x * 256 + threadIdx.x;
  if (e < EE) atomicAdd(&deg[g * NN + ei[e]], 1);
}

// ---------- exclusive scan of deg[NN] -> rp[0..NN], one block per graph ----------
__global__ void scan_kernel(const int* __restrict__ degb, int* __restrict__ rpb){
  const int* deg = degb + blockIdx.x * NN;
  int* rp = rpb + blockIdx.x * (NN + 1);
  __shared__ int part[1024];
  int t = threadIdx.x;
  int base = t * 16;
  int v[16]; int s = 0;
#pragma unroll
  for (int i = 0; i < 16; i++){ v[i] = deg[base + i]; s += v[i]; }
  part[t] = s;
  __syncthreads();
  for (int off = 1; off < 1024; off <<= 1){
    int x = (t >= off) ? part[t - off] : 0;
    __syncthreads();
    part[t] += x;
    __syncthreads();
  }
  int excl = part[t] - s;
#pragma unroll
  for (int i = 0; i < 16; i++){ rp[base + i] = excl; excl += v[i]; }
  if (t == 1023) rp[NN] = part[1023];
}

// ---------- dinv = 1/sqrt(deg+1); cursor init (both graphs) ----------
__global__ void dinv_cur(const int* __restrict__ deg, const int* __restrict__ rp,
                         float* __restrict__ dinv, int* __restrict__ cur){
  int g = blockIdx.y;
  int i = blockIdx.x * 256 + threadIdx.x;
  if (i < NN){
    dinv[g * NN + i] = 1.0f / sqrtf((float)(deg[g * NN + i] + 1));
    cur[g * NN + i] = rp[g * (NN + 1) + i];
  }
}

// ---------- CSR fill (both graphs) ----------
__global__ void fill_kernel(const int* __restrict__ ei0, const int* __restrict__ ei1,
                            int* __restrict__ cur, int* __restrict__ col){
  int g = blockIdx.y;
  const int* ei = g ? ei1 : ei0;
  int e = blockIdx.x * 256 + threadIdx.x;
  if (e < EE){
    int r = ei[e];
    int pos = atomicAdd(&cur[g * NN + r], 1);
    col[g * EE + pos] = ei[EE + e];
  }
}

// ---------- cast features fp32[N][144] -> bf16[2N][160] (zero-padded K) ----------
__global__ void cast_feat(const float* __restrict__ f0, const float* __restrict__ f1,
                          unsigned short* __restrict__ Xb){
  int g = blockIdx.y;
  const float* F = g ? f1 : f0;
  int idx = blockIdx.x * 256 + threadIdx.x;   // quad index over NN*40
  int i = idx / 40, q = idx % 40;
  ushort4 o;
  if (q < 36){
    float4 v = *(const float4*)(F + (size_t)i * DIN + q * 4);
    o.x = f2bf(v.x); o.y = f2bf(v.y); o.z = f2bf(v.z); o.w = f2bf(v.w);
  } else {
    o.x = 0; o.y = 0; o.z = 0; o.w = 0;
  }
  *(ushort4*)(Xb + ((size_t)g * NN + i) * 160 + q * 4) = o;
}

// ---------- W transposes -> bf16 (W1T[128][160] pad, W2T[64][128], W3T[32][64]) ----
__global__ void wtrans(const float* __restrict__ W1, const float* __restrict__ W2,
                       const float* __restrict__ W3, unsigned short* __restrict__ W1T,
                       unsigned short* __restrict__ W2T, unsigned short* __restrict__ W3T){
  int idx = blockIdx.x * 256 + threadIdx.x;  // 0..30719
  if (idx < 20480){
    int f = idx / 160, k = idx % 160;
    W1T[idx] = (k < DIN) ? f2bf(W1[k * F1d + f]) : (unsigned short)0;
  } else if (idx < 28672){
    int r = idx - 20480; int f = r / 128, k = r % 128;
    W2T[r] = f2bf(W2[k * F2d + f]);
  } else if (idx < 30720){
    int r = idx - 28672; int f = r / 64, k = r % 64;
    W3T[r] = f2bf(W3[k * F3d + f]);
  }
}

// ================= hs = bf16( dinv[i] * (X @ W) ), MFMA =================
// Block = 256 thr = 4 waves (2x2). Block tile 128 rows x FD cols; wave tile
// 64 x FD/2. A [2N][KP] bf16 row-major; BT = W^T [FD][KP] bf16 -> both operand
// frags are 16B/lane contiguous loads (layout verified by sim_mfma rounds 2-7).
// C layout: col = l&15, row = (l>>4)*4 + reg (guide m89).
// waves_per_eu(2,2): 256-VGPR budget (acc 64 + frags ~32).
template<int KP, int FD>
__global__ __attribute__((amdgpu_flat_work_group_size(256, 256), amdgpu_waves_per_eu(2, 2)))
void gemm_mfma(const unsigned short* __restrict__ A,
               const unsigned short* __restrict__ BT,
               const float* __restrict__ dinv,
               unsigned short* __restrict__ HS){
  constexpr int NT = FD / 32;     // 16-col tiles per wave
  int t = threadIdx.x;
  int l = t & 63, w = t >> 6;
  int wr = w >> 1, wc = w & 1;
  int i0 = blockIdx.x * 128 + wr * 64;
  int j0 = wc * (FD / 2);
  int m = l & 15;
  int k0 = (l >> 4) * 8;
  int quad = l >> 4;

  f32x4 acc[4][NT];
#pragma unroll
  for (int u = 0; u < 4; u++)
#pragma unroll
    for (int v = 0; v < NT; v++)
      acc[u][v] = (f32x4){0.f, 0.f, 0.f, 0.f};

  for (int kk = 0; kk < KP; kk += 32){
    bf16x8 a[4], b[NT];
#pragma unroll
    for (int u = 0; u < 4; u++)
      a[u] = *(const bf16x8*)(A + (size_t)(i0 + u * 16 + m) * KP + kk + k0);
#pragma unroll
    for (int v = 0; v < NT; v++)
      b[v] = *(const bf16x8*)(BT + (size_t)(j0 + v * 16 + m) * KP + kk + k0);
#pragma unroll
    for (int u = 0; u < 4; u++)
#pragma unroll
      for (int v = 0; v < NT; v++)
        acc[u][v] = __builtin_amdgcn_mfma_f32_16x16x32_bf16(a[u], b[v], acc[u][v], 0, 0, 0);
  }

#pragma unroll
  for (int u = 0; u < 4; u++){
    float dv[4];
#pragma unroll
    for (int r = 0; r < 4; r++)
      dv[r] = dinv[i0 + u * 16 + quad * 4 + r];
#pragma unroll
    for (int v = 0; v < NT; v++){
#pragma unroll
      for (int r = 0; r < 4; r++){
        int row = i0 + u * 16 + quad * 4 + r;
        HS[(size_t)row * FD + j0 + v * 16 + m] = f2bf(acc[u][v][r] * dv[r]);
      }
    }
  }
}

// ---------- out[i] = dinv[i]*(hs[i] + sum_nbr hs[j]) + b, bf16 in/out ----------
template<int FD, bool RELU, bool FP32OUT>
__global__ __launch_bounds__(256) void agg_kernel(const unsigned short* __restrict__ HS,
                                                  const int* __restrict__ rp,
                                                  const int* __restrict__ col,
                                                  const float* __restrict__ dinv,
                                                  const float* __restrict__ b,
                                                  unsigned short* __restrict__ OUTB,
                                                  float* __restrict__ OUTF){
  constexpr int TPN = FD / 4;          // threads per node (4 feats each)
  constexpr int NPB = 256 / TPN;       // nodes per block
  int g = blockIdx.y;
  int t = threadIdx.x;
  int f4 = t % TPN;
  int i = blockIdx.x * NPB + t / TPN;
  const ushort4* HS4 = (const ushort4*)HS;
  size_t gb = (size_t)g * NN;
  ushort4 h0 = HS4[(gb + i) * TPN + f4];
  float ax = bf2f(h0.x), ay = bf2f(h0.y), az = bf2f(h0.z), aw = bf2f(h0.w);
  int p0 = rp[g * (NN + 1) + i], p1 = rp[g * (NN + 1) + i + 1];
  const int* colg = col + (size_t)g * EE;
  for (int p = p0; p < p1; p++){
    int j = colg[p];
    ushort4 h = HS4[(gb + j) * TPN + f4];
    ax += bf2f(h.x); ay += bf2f(h.y); az += bf2f(h.z); aw += bf2f(h.w);
  }
  float di = dinv[g * NN + i];
  float4 bb = ((const float4*)b)[f4];
  float4 o;
  o.x = di * ax + bb.x;
  o.y = di * ay + bb.y;
  o.z = di * az + bb.z;
  o.w = di * aw + bb.w;
  if (RELU){
    o.x = fmaxf(o.x, 0.f); o.y = fmaxf(o.y, 0.f);
    o.z = fmaxf(o.z, 0.f); o.w = fmaxf(o.w, 0.f);
  }
  ushort4 ob;
  ob.x = f2bf(o.x); ob.y = f2bf(o.y); ob.z = f2bf(o.z); ob.w = f2bf(o.w);
  ((ushort4*)OUTB)[(gb + i) * TPN + f4] = ob;
  if (FP32OUT)
    ((float4*)OUTF)[(gb + i) * TPN + f4] = o;
}

// ---------- per-block column-sum partials of af (N x 32), atomic-free ----------
__global__ void colsum_kernel(const float* __restrict__ AF, float* __restrict__ cpart){
  __shared__ float s[8][32];
  int g = blockIdx.y;
  int t = threadIdx.x;
  int f = t % 32;
  int slot = t / 32;
  const float* AFg = AF + (size_t)g * NN * 32;
  float a = 0.f;
  for (int i = blockIdx.x * 8 + slot; i < NN; i += gridDim.x * 8)
    a += AFg[(size_t)i * 32 + f];
  s[slot][f] = a;
  __syncthreads();
  if (t < 32){
    float tot = 0.f;
#pragma unroll
    for (int k = 0; k < 8; k++) tot += s[k][f];
    cpart[((size_t)g * 128 + blockIdx.x) * 32 + f] = tot;
  }
}

// ---------- tg = tanh( (colsum/N) @ att_W ), one block per graph ----------
__global__ void tg_kernel(const float* __restrict__ cpart, const float* __restrict__ attW,
                          float* __restrict__ tgb){
  __shared__ float cs[32];
  int g = blockIdx.x;
  int f = threadIdx.x;   // 32 threads
  float s = 0.f;
  for (int b = 0; b < 128; b++)
    s += cpart[((size_t)g * 128 + b) * 32 + f];
  cs[f] = s * (1.f / (float)NN);
  __syncthreads();
  float acc = 0.f;
  for (int k = 0; k < 32; k++)
    acc += cs[k] * attW[k * 32 + f];
  tgb[g * 32 + f] = tanhf(acc);
}

// ---------- pooled partials: af^T @ sigmoid(af @ tg), atomic-free ----------
__global__ void pool_kernel(const float* __restrict__ AF, const float* __restrict__ tgb,
                            float* __restrict__ ppart){
  __shared__ float s[8][32];
  int g = blockIdx.y;
  int t = threadIdx.x;
  int f = t % 32;
  int slot = t / 32;
  const float* AFg = AF + (size_t)g * NN * 32;
  float tgv = tgb[g * 32 + f];
  float acc = 0.f;
  for (int i = blockIdx.x * 8 + slot; i < NN; i += gridDim.x * 8){
    float v = AFg[(size_t)i * 32 + f];
    float d = v * tgv;
#pragma unroll
    for (int o = 16; o >= 1; o >>= 1) d += __shfl_xor(d, o, 32);
    float gate = 1.f / (1.f + expf(-d));
    acc += v * gate;
  }
  s[slot][f] = acc;
  __syncthreads();
  if (t < 32){
    float tot = 0.f;
#pragma unroll
    for (int k = 0; k < 8; k++) tot += s[k][f];
    ppart[((size_t)g * 128 + blockIdx.x) * 32 + f] = tot;
  }
}

// ================= sim = af1 @ af2^T, persistent, ATOMIC-FREE =================
template<int PASS>
__global__ __attribute__((amdgpu_flat_work_group_size(256, 256), amdgpu_waves_per_eu(4, 4)))
void sim_mfma(const unsigned short* __restrict__ A,
              const unsigned short* __restrict__ B,
              const float* __restrict__ edg,
              float* __restrict__ pmm,
              unsigned* __restrict__ phist){
  __shared__ unsigned lh[4][16][64];      // 16 KB; used in PASS 2
  __shared__ unsigned red[16][16];
  int t = threadIdx.x;
  int l = t & 63, w = t >> 6;
  int wave_id = blockIdx.x * 4 + w;
  int istrip = wave_id >> 4;
  int jgrp = wave_id & 15;
  int i0 = istrip * 64;
  int m  = l & 15;
  int k0 = (l >> 4) * 8;

  unsigned* myslot = &lh[w][0][l];        // stride 64 u32 between bins
  if (PASS == 2){
#pragma unroll
    for (int q = 0; q < 16; q++) myslot[q * 64] = 0u;
  }

  bf16x8 a[4];
#pragma unroll
  for (int u = 0; u < 4; u++)
    a[u] = *(const bf16x8*)(A + (size_t)(i0 + u * 16 + m) * 32 + k0);

  float mn = 3.402823466e38f, mx = -3.402823466e38f;
  float off = 0.f, sc = 0.f;
  if (PASS == 2){ off = edg[0]; sc = edg[1]; }

  for (int jj = 0; jj < 16; jj++){
    int j0 = (jgrp * 16 + jj) * 64;
    bf16x8 b[4];
#pragma unroll
    for (int v = 0; v < 4; v++)
      b[v] = *(const bf16x8*)(B + (size_t)(j0 + v * 16 + m) * 32 + k0);

    if (PASS == 1){
#pragma unroll
      for (int u = 0; u < 4; u++)
#pragma unroll
        for (int v = 0; v < 4; v++){
          f32x4 z = {0.f, 0.f, 0.f, 0.f};
          f32x4 acc = __builtin_amdgcn_mfma_f32_16x16x32_bf16(a[u], b[v], z, 0, 0, 0);
          mn = fminf(fminf(acc[0], acc[1]), mn);   // v_min3
          mn = fminf(fminf(acc[2], acc[3]), mn);
          mx = fmaxf(fmaxf(acc[0], acc[1]), mx);   // v_max3
          mx = fmaxf(fmaxf(acc[2], acc[3]), mx);
        }
    } else {
#pragma unroll
      for (int u = 0; u < 4; u++)
#pragma unroll
        for (int v = 0; v < 4; v++){
          f32x4 z = {0.f, 0.f, 0.f, 0.f};
          f32x4 acc = __builtin_amdgcn_mfma_f32_16x16x32_bf16(a[u], b[v], z, 0, 0, 0);
#pragma unroll
          for (int r = 0; r < 4; r++){
            int idx = (int)__builtin_amdgcn_fmed3f(fmaf(acc[r], sc, off), 0.f, 15.f);
            atomicAdd(&myslot[idx * 64], 1u);
          }
        }
    }
  }

  if (PASS == 1){
#pragma unroll
    for (int o = 32; o >= 1; o >>= 1){
      mn = fminf(mn, __shfl_xor(mn, o));
      mx = fmaxf(mx, __shfl_xor(mx, o));
    }
    __shared__ float wmn[4], wmx[4];
    if (l == 0){ wmn[w] = mn; wmx[w] = mx; }
    __syncthreads();
    if (t == 0){
      float bmn = fminf(fminf(wmn[0], wmn[1]), fminf(wmn[2], wmn[3]));
      float bmx = fmaxf(fmaxf(wmx[0], wmx[1]), fmaxf(wmx[2], wmx[3]));
      pmm[blockIdx.x * 2]     = bmn;
      pmm[blockIdx.x * 2 + 1] = bmx;
    }
  } else {
    __syncthreads();
    int bin = t & 15, part = t >> 4;
    unsigned s = 0;
#pragma unroll
    for (int ww = 0; ww < 4; ww++)
#pragma unroll
      for (int lc = 0; lc < 4; lc++)
        s += lh[ww][bin][part * 4 + lc];
    red[part][bin] = s;
    __syncthreads();
    if (t < 16){
      unsigned tot = 0;
#pragma unroll
      for (int p = 0; p < 16; p++) tot += red[p][t];
      phist[blockIdx.x * 16 + t] = tot;
    }
  }
}

// ---------- reduce per-block min/max partials -> (off, sc) ----------
__global__ void edges_kernel(const float* __restrict__ pmm, float* __restrict__ edg){
  int t = threadIdx.x;
  float mn = 3.402823466e38f, mx = -3.402823466e38f;
  for (int b = t; b < SIM_BLOCKS; b += 256){
    mn = fminf(mn, pmm[b * 2]);
    mx = fmaxf(mx, pmm[b * 2 + 1]);
  }
#pragma unroll
  for (int o = 32; o >= 1; o >>= 1){
    mn = fminf(mn, __shfl_xor(mn, o));
    mx = fmaxf(mx, __shfl_xor(mx, o));
  }
  __shared__ float wmn[4], wmx[4];
  if ((t & 63) == 0){ wmn[t >> 6] = mn; wmx[t >> 6] = mx; }
  __syncthreads();
  if (t == 0){
    float lo = fminf(fminf(wmn[0], wmn[1]), fminf(wmn[2], wmn[3]));
    float hi = fmaxf(fmaxf(wmx[0], wmx[1]), fmaxf(wmx[2], wmx[3]));
    float sc = (hi > lo) ? (16.f / (hi - lo)) : 0.f;
    edg[0] = -lo * sc;   // off
    edg[1] = sc;
  }
}

// ---------- final: pooled reduce + hist reduce + tnet + fc + sigmoid ----------
__global__ void final_kernel(const float* __restrict__ ppart, const unsigned* __restrict__ phist,
                             const float* __restrict__ tW, const float* __restrict__ tWb,
                             const float* __restrict__ tb,
                             const float* __restrict__ fcW, const float* __restrict__ fcb,
                             const float* __restrict__ scW, const float* __restrict__ scb,
                             float* __restrict__ out){
  __shared__ float e[2][32], v32[32], uu[16], hn[16];
  __shared__ unsigned htmp[256];
  __shared__ float4 accL[256];
  int t = threadIdx.x;  // 256

  if (t < 64){
    int g = t >> 5, f = t & 31;
    float s = 0.f;
    for (int b = 0; b < 128; b++)
      s += ppart[((size_t)g * 128 + b) * 32 + f];
    e[g][f] = s;
  }
  {
    int bin = t & 15;
    unsigned hs = 0;
    for (int b = t >> 4; b < SIM_BLOCKS; b += 16)
      hs += phist[b * 16 + bin];
    htmp[t] = hs;
  }
  __syncthreads();

  if (t < 16){
    unsigned c = 0;
#pragma unroll
    for (int p = 0; p < 16; p++) c += htmp[p * 16 + t];
    hn[t] = (float)c;
  }

  const float4* tw4 = (const float4*)tW;
  float4 acc = {0.f, 0.f, 0.f, 0.f};
#pragma unroll
  for (int i = 0; i < 16; i++){
    int idx = t + 256 * i;
    int pair = idx >> 2;
    float coef = e[0][pair >> 5] * e[1][pair & 31];
    float4 w4 = tw4[idx];
    acc.x += coef * w4.x; acc.y += coef * w4.y;
    acc.z += coef * w4.z; acc.w += coef * w4.w;
  }
  accL[t] = acc;
  __syncthreads();

  if (t < 16){
    int q = t >> 2, r = t & 3;
    float s = 0.f;
    for (int j = 0; j < 64; j++){
      float4 a4 = accL[q + 4 * j];
      s += (r == 0) ? a4.x : (r == 1) ? a4.y : (r == 2) ? a4.z : a4.w;
    }
    float blk = 0.f;
    for (int a = 0; a < 32; a++) blk += tWb[t * 64 + a] * e[0][a];
    for (int b = 0; b < 32; b++) blk += tWb[t * 64 + 32 + b] * e[1][b];
    float rr = s + blk + tb[t];
    v32[t] = rr > 0.f ? rr : 0.f;
  }
  __syncthreads();

  if (t < 16){
    float tot = 0.f;
#pragma unroll
    for (int i = 0; i < 16; i++) tot += hn[i];
    float inv = 1.f / tot;
    float s = fcb[t];
    for (int i = 0; i < 16; i++) s += fcW[t * 32 + i] * v32[i];
    for (int i = 0; i < 16; i++) s += fcW[t * 32 + 16 + i] * (hn[i] * inv);
    uu[t] = s > 0.f ? s : 0.f;
  }
  __syncthreads();
  if (t == 0){
    float s = scb[0];
    for (int i = 0; i < 16; i++) s += scW[i] * uu[i];
    out[0] = 1.f / (1.f + expf(-s));
  }
}

extern "C" void kernel_launch(void* const* d_in, const int* in_sizes, int n_in,
                              void* d_out, int out_size, void* d_ws, size_t ws_size,
                              hipStream_t stream){
  const float* feat0 = (const float*)d_in[0];
  const float* feat1 = (const float*)d_in[1];
  const int*   ei0   = (const int*)d_in[2];
  const int*   ei1   = (const int*)d_in[3];
  const float* W1  = (const float*)d_in[4];
  const float* b1  = (const float*)d_in[5];
  const float* W2  = (const float*)d_in[6];
  const float* b2  = (const float*)d_in[7];
  const float* W3  = (const float*)d_in[8];
  const float* b3  = (const float*)d_in[9];
  const float* attW = (const float*)d_in[10];
  const float* tW  = (const float*)d_in[11];
  const float* tWb = (const float*)d_in[12];
  const float* tb  = (const float*)d_in[13];
  const float* fcW = (const float*)d_in[14];
  const float* fcb = (const float*)d_in[15];
  const float* scW = (const float*)d_in[16];
  const float* scb = (const float*)d_in[17];

  char* w = (char*)d_ws;
  size_t o = 0;
  auto alloc = [&](size_t bytes)->char*{
    char* p = w + o; o += (bytes + 255) & ~(size_t)255; return p;
  };
  int* deg   = (int*)alloc((size_t)2 * NN * 4);
  int* rp    = (int*)alloc((size_t)2 * (NN + 1) * 4);
  int* cur   = (int*)alloc((size_t)2 * NN * 4);
  int* col   = (int*)alloc((size_t)2 * EE * 4);
  float* dinv = (float*)alloc((size_t)2 * NN * 4);
  unsigned short* Xb  = (unsigned short*)alloc((size_t)2 * NN * 160 * 2);
  unsigned short* W1T = (unsigned short*)alloc((size_t)128 * 160 * 2);
  unsigned short* W2T = (unsigned short*)alloc((size_t)64 * 128 * 2);
  unsigned short* W3T = (unsigned short*)alloc((size_t)32 * 64 * 2);
  unsigned short* hs  = (unsigned short*)alloc((size_t)2 * NN * F1d * 2);
  unsigned short* ab1 = (unsigned short*)alloc((size_t)2 * NN * F1d * 2);
  unsigned short* ab2 = (unsigned short*)alloc((size_t)2 * NN * F2d * 2);
  unsigned short* afb = (unsigned short*)alloc((size_t)2 * NN * F3d * 2);
  float* af    = (float*)alloc((size_t)2 * NN * F3d * 4);
  float* cpart = (float*)alloc((size_t)2 * 128 * 32 * 4);
  float* ppart = (float*)alloc((size_t)2 * 128 * 32 * 4);
  float* pmm   = (float*)alloc((size_t)SIM_BLOCKS * 2 * 4);
  unsigned* phist = (unsigned*)alloc((size_t)SIM_BLOCKS * 16 * 4);
  float* smallf = (float*)alloc(256 * 4);
  float* tgb = smallf;        // [2][32]
  float* edg = smallf + 64;   // off, sc

  init_kernel<<<128, 256, 0, stream>>>(deg);
  deg_count<<<dim3(EE / 256, 2), 256, 0, stream>>>(ei0, ei1, deg);
  scan_kernel<<<2, 1024, 0, stream>>>(deg, rp);
  dinv_cur<<<dim3(NN / 256, 2), 256, 0, stream>>>(deg, rp, dinv, cur);
  fill_kernel<<<dim3(EE / 256, 2), 256, 0, stream>>>(ei0, ei1, cur, col);

  cast_feat<<<dim3(NN * 40 / 256, 2), 256, 0, stream>>>(feat0, feat1, Xb);
  wtrans<<<120, 256, 0, stream>>>(W1, W2, W3, W1T, W2T, W3T);

  gemm_mfma<160, F1d><<<2 * NN / 128, 256, 0, stream>>>(Xb, W1T, dinv, hs);
  agg_kernel<F1d, true, false><<<dim3(NN / 8, 2), 256, 0, stream>>>(hs, rp, col, dinv, b1, ab1, nullptr);
  gemm_mfma<128, F2d><<<2 * NN / 128, 256, 0, stream>>>(ab1, W2T, dinv, hs);
  agg_kernel<F2d, true, false><<<dim3(NN / 16, 2), 256, 0, stream>>>(hs, rp, col, dinv, b2, ab2, nullptr);
  gemm_mfma<64, F3d><<<2 * NN / 128, 256, 0, stream>>>(ab2, W3T, dinv, hs);
  agg_kernel<F3d, false, true><<<dim3(NN / 32, 2), 256, 0, stream>>>(hs, rp, col, dinv, b3, afb, af);

  colsum_kernel<<<dim3(128, 2), 256, 0, stream>>>(af, cpart);
  tg_kernel<<<2, 32, 0, stream>>>(cpart, attW, tgb);
  pool_kernel<<<dim3(128, 2), 256, 0, stream>>>(af, tgb, ppart);

  const unsigned short* afb0 = afb;
  const unsigned short* afb1 = afb + (size_t)NN * F3d;
  sim_mfma<1><<<SIM_BLOCKS, 256, 0, stream>>>(afb0, afb1, edg, pmm, phist);
  edges_kernel<<<1, 256, 0, stream>>>(pmm, edg);
  sim_mfma<2><<<SIM_BLOCKS, 256, 0, stream>>>(afb0, afb1, edg, pmm, phist);

  final_kernel<<<1, 256, 0, stream>>>(ppart, phist, tW, tWb, tb,
                                      fcW, fcb, scW, scb, (float*)d_out);
}